// Round 7
// baseline (5775.265 us; speedup 1.0000x reference)
//
#include <hip/hip_runtime.h>
#include <hip/hip_bf16.h>
#include <math.h>

// ---------------------------------------------------------------------------
// Bi-LSTM encoder (final states only) -> 2-layer AR decoder (64 steps) -> vocab-3.
//   init_k        : zero decoder input buf / flags (every call)
//   convert_k     : x, ew_ih_{f,b} -> f16; bias sums
//   convert_we2_k : enc W_hh -> per-wave MFMA A-fragments (f16), frag-major
//   convert_wd_k  : dec [W_ih|W_hh] -> packed f16 pairs
//   xproj_gemm    : f16 MFMA GEMM -> Xproj[dir][t][b][1024] fp32 (+bias), dir1 reversed
//   encoder_k     : v6 — 16 SELF-CONTAINED blocks (d x 16-row group), 512 thr;
//                   full W_hh per block: 128 VGPR + 128 KB LDS + 128 KB/step L2 stream;
//                   operand-swapped MFMA (D[gcol][brow]) -> register-local epilogue;
//                   h via 16 KB LDS dbuf; ONE barrier/step; zero cross-block sync
//   decoder_k     : persistent (L,bg,jg) blocks, f16 dot2, relaxed-atomic flag sync
//   logits_k      : h1 history @ lw^T + lb
// ---------------------------------------------------------------------------

typedef unsigned short u16;
typedef unsigned int u32;
typedef unsigned long long u64;
typedef _Float16 f16;
typedef f16 f16x8 __attribute__((ext_vector_type(8)));
typedef f16 f16x2 __attribute__((ext_vector_type(2)));
typedef u16 u16x8 __attribute__((ext_vector_type(8)));
typedef u32 u32x4 __attribute__((ext_vector_type(4)));
typedef float f32x4 __attribute__((ext_vector_type(4)));

__device__ __forceinline__ u16 f2h(float f) {
  return __builtin_bit_cast(unsigned short, (f16)f);
}
__device__ __forceinline__ u32 packf16(float a, float b) {
  return (u32)f2h(a) | ((u32)f2h(b) << 16);
}
__device__ __forceinline__ float dot2(u32 h, u32 w, float c) {
  return __builtin_amdgcn_fdot2(__builtin_bit_cast(f16x2, h),
                                __builtin_bit_cast(f16x2, w), c, false);
}

// ---------------------------------------------------------------------------
__global__ __launch_bounds__(256) void init_k(float* inpb, int* df) {
  int gid = blockIdx.x * 256 + threadIdx.x;   // grid 256*256 = 65536
  inpb[gid] = 0.f;
  if (gid < 256) df[gid] = 0;
}

// ---------------------------------------------------------------------------
__global__ __launch_bounds__(256) void convert_k(
    const float* __restrict__ x,
    const float* __restrict__ wfm, const float* __restrict__ wbm,
    const float* __restrict__ bif, const float* __restrict__ bhf,
    const float* __restrict__ bib, const float* __restrict__ bhb,
    const float* __restrict__ dbi0, const float* __restrict__ dbh0,
    const float* __restrict__ dbi1, const float* __restrict__ dbh1,
    u16* __restrict__ xh, u16* __restrict__ wh,
    float* __restrict__ bias2, float* __restrict__ dbias) {
  const long NX = 67108864L, NW = 1048576L;
  long gid = (long)blockIdx.x * 256 + threadIdx.x;
  if (gid < 1024) {
    bias2[gid]        = bif[gid] + bhf[gid];
    bias2[1024 + gid] = bib[gid] + bhb[gid];
    dbias[gid]        = dbi0[gid] + dbh0[gid];
    dbias[1024 + gid] = dbi1[gid] + dbh1[gid];
  }
  long total4 = (NX + 2 * NW) >> 2;
  long stride = (long)gridDim.x * 256;
  for (long q = gid; q < total4; q += stride) {
    long i = q << 2;
    const float* src; u16* dst; long o;
    if (i < NX)            { src = x;   dst = xh;      o = i; }
    else if (i < NX + NW)  { src = wfm; dst = wh;      o = i - NX; }
    else                   { src = wbm; dst = wh + NW; o = i - NX - NW; }
    float4 v = *(const float4*)&src[o];
    dst[o + 0] = f2h(v.x); dst[o + 1] = f2h(v.y);
    dst[o + 2] = f2h(v.z); dst[o + 3] = f2h(v.w);
  }
}

// ---------------------------------------------------------------------------
// enc W_hh -> per-wave A-fragments, frag-major for coalesced streaming:
//   wenc2[d][w][f][lane][j], f = ks*8 + g*2 + ch  (64 frags/wave)
//   = W_hh_d[g*256 + w*32 + ch*16 + (lane&15)][ks*32 + (lane>>4)*8 + j]
__global__ __launch_bounds__(256) void convert_we2_k(
    const float* __restrict__ whf, const float* __restrict__ whb,
    u16* __restrict__ wenc2) {
  int o = blockIdx.x * 256 + threadIdx.x;     // grid 2048*256 = 524288
  int j = o & 7, lane = (o >> 3) & 63, f = (o >> 9) & 63;
  int w = (o >> 15) & 7, d = (o >> 18) & 1;
  int ks = f >> 3, g = (f >> 1) & 3, ch = f & 1;
  const float* wsrc = d ? whb : whf;
  int row = g * 256 + w * 32 + ch * 16 + (lane & 15);
  int k = ks * 32 + (lane >> 4) * 8 + j;
  wenc2[o] = f2h(wsrc[row * 256 + k]);
}

// ---------------------------------------------------------------------------
// dec [W_ih|W_hh] -> packed f16 pairs: dwf16[L(2)][ks(16)][kp(16)][g(4)][c(256)]
__global__ __launch_bounds__(256) void convert_wd_k(
    const float* __restrict__ wi0, const float* __restrict__ wh0,
    const float* __restrict__ wi1, const float* __restrict__ wh1,
    u32* __restrict__ dwf16) {
  int i = blockIdx.x * 256 + threadIdx.x;     // grid 2048*256 = 524288
  int L = i >> 18, ks = (i >> 14) & 15, kp = (i >> 10) & 15;
  int g = (i >> 8) & 3, c = i & 255;
  int grow = g * 256 + c;
  int kk = (ks * 16 + kp) * 2;
  const float* wi = L ? wi1 : wi0;
  const float* wh = L ? wh1 : wh0;
  const float* s = (kk < 256) ? &wi[grow * 256 + kk] : &wh[grow * 256 + kk - 256];
  dwf16[i] = packf16(s[0], s[1]);
}

// ---------------------------------------------------------------------------
// Xproj GEMM (f16): C = X @ W^T + bias, 128x128 tiles, mfma_f32_16x16x32_f16.
__global__ __launch_bounds__(256) void xproj_gemm(
    const u16* __restrict__ xh, const u16* __restrict__ wh,
    const float* __restrict__ bias2, float* __restrict__ xp) {
  __shared__ u16 Al[128][40];
  __shared__ u16 Bl[128][40];
  int bid = blockIdx.x;
  int dir = bid >> 12, rem = bid & 4095, tb = rem >> 3, nb = rem & 7;
  int tsrc = dir ? (511 - tb) : tb;
  const u16* A  = xh + (long)tsrc * (128 * 1024);
  const u16* Bw = wh + (long)dir * (1024 * 1024) + (long)nb * (128 * 1024);
  float* C = xp + ((long)(dir * 512 + tb) * 128) * 1024 + nb * 128;
  const float* bias = bias2 + dir * 1024 + nb * 128;

  int tid = threadIdx.x, lane = tid & 63, wid = tid >> 6;
  int wr = wid >> 1, wc = wid & 1;
  int srow = tid >> 1, scol = (tid & 1) * 16;
  int fr = lane & 15, ko = lane >> 4;

  f32x4 acc[4][4] = {};
  for (int k0 = 0; k0 < 1024; k0 += 32) {
    u16x8 a0 = *(const u16x8*)&A[(long)srow * 1024 + k0 + scol];
    u16x8 a1 = *(const u16x8*)&A[(long)srow * 1024 + k0 + scol + 8];
    u16x8 b0 = *(const u16x8*)&Bw[(long)srow * 1024 + k0 + scol];
    u16x8 b1 = *(const u16x8*)&Bw[(long)srow * 1024 + k0 + scol + 8];
    __syncthreads();
    *(u16x8*)&Al[srow][scol]     = a0;
    *(u16x8*)&Al[srow][scol + 8] = a1;
    *(u16x8*)&Bl[srow][scol]     = b0;
    *(u16x8*)&Bl[srow][scol + 8] = b1;
    __syncthreads();
    f16x8 af[4], bf[4];
#pragma unroll
    for (int i = 0; i < 4; ++i)
      af[i] = __builtin_bit_cast(f16x8, *(const u16x8*)&Al[wr * 64 + i * 16 + fr][ko * 8]);
#pragma unroll
    for (int jf = 0; jf < 4; ++jf)
      bf[jf] = __builtin_bit_cast(f16x8, *(const u16x8*)&Bl[wc * 64 + jf * 16 + fr][ko * 8]);
#pragma unroll
    for (int i = 0; i < 4; ++i)
#pragma unroll
      for (int jf = 0; jf < 4; ++jf)
        acc[i][jf] = __builtin_amdgcn_mfma_f32_16x16x32_f16(af[i], bf[jf], acc[i][jf], 0, 0, 0);
  }
  int fq = lane >> 4;
#pragma unroll
  for (int i = 0; i < 4; ++i)
#pragma unroll
    for (int jf = 0; jf < 4; ++jf) {
      int col = wc * 64 + jf * 16 + fr;
      float bv = bias[col];
#pragma unroll
      for (int e = 0; e < 4; ++e) {
        int row = wr * 64 + i * 16 + fq * 4 + e;
        C[(long)row * 1024 + col] = acc[i][jf][e] + bv;
      }
    }
}

// ---------------------------------------------------------------------------
// Encoder v6: 16 blocks = d(2) x bg(8; 16 batch rows), 512 threads (8 waves).
// Wave w owns h-cols [w*32, w*32+32): tiles (g 4) x (ch 2), K=256 in 8 k-steps.
// Operand-swapped MFMA: D = A(W: 16 gcols x 32k) x B(h^T: 32k x 16 brows)
//   -> lane holds brow = lane&15, gcol = base + (lane>>4)*4 + e  (register-local
//   epilogue: all 4 gates of a cell in-lane across acc[g*2+ch]).
// W_hh split: frags f=0..31 (ks0-3) resident in 128 VGPR; f=32..47 (ks4,5) in
// 128 KB LDS (filled once); f=48..63 (ks6,7) streamed from L2 each step.
// h: 16 KB LDS double-buffer, XOR-swizzled. One barrier per step. No global sync.
__global__ __launch_bounds__(512, 2) void encoder_k(
    const u16* __restrict__ wenc2, const float* __restrict__ xp,
    float* h0b, float* h1b, float* cfb, float* cbb) {
  __shared__ __align__(16) u16 wlds[8][16][64][8];   // 128 KB: [wave][frag][lane][8]
  __shared__ __align__(16) char hbuf[2][8192];       // h [16 brow][256 col] f16, swz

  int b = blockIdx.x;              // 0..15
  int d = b >> 3, bg = b & 7;
  int tid = threadIdx.x, lane = tid & 63, w = tid >> 6;
  int brow = lane & 15, lq = lane >> 4;
  int hswz = (brow & 7) << 4;

  const u16* wbase = wenc2 + (((long)(d * 8 + w)) << 15) + lane * 8;  // + f*512

  // resident W frags (ks 0..3): 32 x f16x8 = 128 VGPR, statically indexed
  f16x8 wfr[32];
#pragma unroll
  for (int f = 0; f < 32; ++f)
    wfr[f] = __builtin_bit_cast(f16x8, *(const u16x8*)(wbase + (long)f * 512));

  // LDS W frags (ks 4,5): fill once
#pragma unroll
  for (int i = 0; i < 16; ++i)
    *(u16x8*)&wlds[w][i][lane][0] = *(const u16x8*)(wbase + (long)(32 + i) * 512);

  // h_0 = 0
  *(u32x4*)(hbuf[0] + tid * 16) = (u32x4){0, 0, 0, 0};

  float c_state[2][4];
#pragma unroll
  for (int ch = 0; ch < 2; ++ch)
#pragma unroll
    for (int e = 0; e < 4; ++e) c_state[ch][e] = 0.f;

  const float* xprow = xp + ((long)(d * 512) * 128 + bg * 16 + brow) * 1024;
  __syncthreads();

  for (int t = 0; t < 512; ++t) {
    const char* hrd = hbuf[t & 1];
    char* hwr = hbuf[(t + 1) & 1];
    const float* xpt = xprow + (long)t * 131072;

    // issue stream batch 1 (ks6: frags 48..55)
    u16x8 sfA[8];
#pragma unroll
    for (int i = 0; i < 8; ++i)
      sfA[i] = *(const u16x8*)(wbase + (long)(48 + i) * 512);
    // issue xp loads (consumed in epilogue)
    f32x4 xpv[8];
#pragma unroll
    for (int g = 0; g < 4; ++g)
#pragma unroll
      for (int ch = 0; ch < 2; ++ch)
        xpv[g * 2 + ch] = *(const f32x4*)&xpt[g * 256 + w * 32 + ch * 16 + lq * 4];

    f32x4 acc[8] = {};   // [g*2+ch]

    // ks 0..3: W from VGPR
#pragma unroll
    for (int ks = 0; ks < 4; ++ks) {
      f16x8 hf = *(const f16x8*)(hrd + ((brow * 512 + ks * 64 + lq * 16) ^ hswz));
#pragma unroll
      for (int f8 = 0; f8 < 8; ++f8)
        acc[f8] = __builtin_amdgcn_mfma_f32_16x16x32_f16(wfr[ks * 8 + f8], hf, acc[f8], 0, 0, 0);
    }
    // ks 4,5: W from LDS
#pragma unroll
    for (int ks = 4; ks < 6; ++ks) {
      f16x8 hf = *(const f16x8*)(hrd + ((brow * 512 + ks * 64 + lq * 16) ^ hswz));
#pragma unroll
      for (int f8 = 0; f8 < 8; ++f8) {
        f16x8 wf = __builtin_bit_cast(f16x8, *(const u16x8*)&wlds[w][(ks - 4) * 8 + f8][lane][0]);
        acc[f8] = __builtin_amdgcn_mfma_f32_16x16x32_f16(wf, hf, acc[f8], 0, 0, 0);
      }
    }
    // ks 6: consume stream batch 1; issue batch 2 (ks7: frags 56..63)
    u16x8 sfB[8];
#pragma unroll
    for (int i = 0; i < 8; ++i)
      sfB[i] = *(const u16x8*)(wbase + (long)(56 + i) * 512);
    {
      f16x8 hf = *(const f16x8*)(hrd + ((brow * 512 + 6 * 64 + lq * 16) ^ hswz));
#pragma unroll
      for (int f8 = 0; f8 < 8; ++f8)
        acc[f8] = __builtin_amdgcn_mfma_f32_16x16x32_f16(
            __builtin_bit_cast(f16x8, sfA[f8]), hf, acc[f8], 0, 0, 0);
    }
    // ks 7: consume stream batch 2
    {
      f16x8 hf = *(const f16x8*)(hrd + ((brow * 512 + 7 * 64 + lq * 16) ^ hswz));
#pragma unroll
      for (int f8 = 0; f8 < 8; ++f8)
        acc[f8] = __builtin_amdgcn_mfma_f32_16x16x32_f16(
            __builtin_bit_cast(f16x8, sfB[f8]), hf, acc[f8], 0, 0, 0);
    }

    // epilogue: register-local LSTM cell; lane covers 8 cells (ch, e)
#pragma unroll
    for (int ch = 0; ch < 2; ++ch) {
      u16 hpk[4];
#pragma unroll
      for (int e = 0; e < 4; ++e) {
        float g0 = acc[0 + ch][e] + xpv[0 + ch][e];
        float g1 = acc[2 + ch][e] + xpv[2 + ch][e];
        float g2 = acc[4 + ch][e] + xpv[4 + ch][e];
        float g3 = acc[6 + ch][e] + xpv[6 + ch][e];
        float iv = 1.f / (1.f + expf(-g0));
        float fv = 1.f / (1.f + expf(-g1));
        float gg = tanhf(g2);
        float ov = 1.f / (1.f + expf(-g3));
        float c2 = fv * c_state[ch][e] + iv * gg;
        c_state[ch][e] = c2;
        float hv = ov * tanhf(c2);
        hpk[e] = f2h(hv);
        if (t == 511) {
          int rowg = bg * 16 + brow;
          int colg = w * 32 + ch * 16 + lq * 4 + e;
          (d ? h1b : h0b)[32768 + rowg * 256 + colg] = hv;
          (d ? cbb : cfb)[rowg * 256 + colg] = c2;
        }
      }
      int hcol = w * 32 + ch * 16 + lq * 4;
      u64 pk = (u64)hpk[0] | ((u64)hpk[1] << 16) | ((u64)hpk[2] << 32) | ((u64)hpk[3] << 48);
      *(u64*)(hwr + ((brow * 512 + hcol * 2) ^ hswz)) = pk;
    }
    __syncthreads();
  }
}

// ---------------------------------------------------------------------------
// Decoder (R2, proven): 256 blocks = L(2) x bg(16) x jg(8), 512 thr.
__global__ __launch_bounds__(512) void decoder_k(
    const u32* __restrict__ dwf16, const float* __restrict__ dbias,
    float* h0b, float* h1b, float* inpb,
    const float* __restrict__ cfb, const float* __restrict__ cbb,
    float* hist, int* df) {
  int bid = blockIdx.x;
  int L = bid >> 7, bg = (bid >> 3) & 15, jg = bid & 7;
  int tid = threadIdx.x;
  int j = tid & 31, ks = tid >> 5;

  u32 w2[4][16];
  {
    const u32* p = dwf16 + (long)(L * 16 + ks) * 16384 + jg * 32 + j;
#pragma unroll
    for (int kp = 0; kp < 16; ++kp)
#pragma unroll
      for (int g = 0; g < 4; ++g)
        w2[g][kp] = p[(kp * 4 + g) * 256];
  }

  __shared__ u32 xl[8][256];
  __shared__ float red[16][8][4][32];
  float c_state = 0.f;
  if (tid < 256)
    c_state = (L ? cbb : cfb)[(bg * 8 + (tid >> 5)) * 256 + jg * 32 + (tid & 31)];
  int srow = tid >> 6, sk8 = (tid & 63) * 8;

  for (int t = 0; t < 64; ++t) {
    if (tid < 16) {
      int p = tid & 7, which = tid >> 3;
      int need = (which == 0) ? ((L == 0) ? t : t + 1) : t;
      int* fp = &df[which * 128 + bg * 8 + p];
      while (__hip_atomic_load(fp, __ATOMIC_RELAXED, __HIP_MEMORY_SCOPE_AGENT) < need)
        __builtin_amdgcn_s_sleep(1);
    }
    __syncthreads();
    {
      const float* xsrc  = (L == 0) ? inpb + (t & 1) * 32768 : h0b + (t & 1) * 32768;
      const float* hsrc2 = (L == 0) ? h0b + ((t + 1) & 1) * 32768 : h1b + ((t + 1) & 1) * 32768;
      const float* s = (sk8 < 256) ? &xsrc[(bg * 8 + srow) * 256 + sk8]
                                   : &hsrc2[(bg * 8 + srow) * 256 + sk8 - 256];
      u32 pk[4];
#pragma unroll
      for (int q = 0; q < 4; ++q) {
        float v0 = __hip_atomic_load(&s[2 * q],     __ATOMIC_RELAXED, __HIP_MEMORY_SCOPE_AGENT);
        float v1 = __hip_atomic_load(&s[2 * q + 1], __ATOMIC_RELAXED, __HIP_MEMORY_SCOPE_AGENT);
        pk[q] = packf16(v0, v1);
      }
      *(u32x4*)&xl[srow][(tid & 63) * 4] = (u32x4){pk[0], pk[1], pk[2], pk[3]};
    }
    __syncthreads();

    float acc[8][4] = {};
#pragma unroll
    for (int r = 0; r < 8; ++r) {
#pragma unroll
      for (int kc = 0; kc < 4; ++kc) {
        const u32* hq = &xl[r][ks * 16 + kc * 4];
        u32 q0 = hq[0], q1 = hq[1], q2 = hq[2], q3 = hq[3];
#pragma unroll
        for (int g = 0; g < 4; ++g) {
          acc[r][g] = dot2(q0, w2[g][kc * 4 + 0], acc[r][g]);
          acc[r][g] = dot2(q1, w2[g][kc * 4 + 1], acc[r][g]);
          acc[r][g] = dot2(q2, w2[g][kc * 4 + 2], acc[r][g]);
          acc[r][g] = dot2(q3, w2[g][kc * 4 + 3], acc[r][g]);
        }
      }
    }
#pragma unroll
    for (int r = 0; r < 8; ++r)
#pragma unroll
      for (int g = 0; g < 4; ++g)
        red[ks][r][g][j] = acc[r][g];
    __syncthreads();

    if (tid < 256) {
      int re = tid >> 5, je = tid & 31;
      float gv[4];
#pragma unroll
      for (int g = 0; g < 4; ++g) {
        float sum = dbias[L * 1024 + g * 256 + jg * 32 + je];
#pragma unroll
        for (int p = 0; p < 16; ++p) sum += red[p][re][g][je];
        gv[g] = sum;
      }
      float iv = 1.f / (1.f + expf(-gv[0]));
      float fv = 1.f / (1.f + expf(-gv[1]));
      float gt = tanhf(gv[2]);
      float ov = 1.f / (1.f + expf(-gv[3]));
      c_state = fv * c_state + iv * gt;
      float hval = ov * tanhf(c_state);
      int rowg = bg * 8 + re, colg = jg * 32 + je;
      if (L == 0) {
        __hip_atomic_store(&h0b[(t & 1) * 32768 + rowg * 256 + colg], hval,
                           __ATOMIC_RELAXED, __HIP_MEMORY_SCOPE_AGENT);
      } else {
        __hip_atomic_store(&h1b[(t & 1) * 32768 + rowg * 256 + colg], hval,
                           __ATOMIC_RELAXED, __HIP_MEMORY_SCOPE_AGENT);
        __hip_atomic_store(&inpb[((t + 1) & 1) * 32768 + rowg * 256 + colg], hval,
                           __ATOMIC_RELAXED, __HIP_MEMORY_SCOPE_AGENT);
        hist[((long)t * 128 + rowg) * 256 + colg] = hval;
      }
    }
    asm volatile("s_waitcnt vmcnt(0)" ::: "memory");
    __syncthreads();
    if (tid == 0)
      __hip_atomic_store(&df[L * 128 + bg * 8 + jg], t + 1,
                         __ATOMIC_RELAXED, __HIP_MEMORY_SCOPE_AGENT);
  }
}

// ---------------------------------------------------------------------------
__global__ __launch_bounds__(256) void logits_k(
    const float* __restrict__ hist, const float* __restrict__ lw,
    const float* __restrict__ lb, float* __restrict__ out) {
  int widx = threadIdx.x >> 6, lane = threadIdx.x & 63;
  int row = blockIdx.x * 4 + widx;
  const float* h = hist + (long)row * 256;
  float4 hv = *(const float4*)&h[lane * 4];
  float s[3];
#pragma unroll
  for (int v = 0; v < 3; ++v) {
    float4 wv = *(const float4*)&lw[v * 256 + lane * 4];
    float p = hv.x * wv.x + hv.y * wv.y + hv.z * wv.z + hv.w * wv.w;
#pragma unroll
    for (int o = 32; o > 0; o >>= 1) p += __shfl_xor(p, o, 64);
    s[v] = p;
  }
  if (lane == 0) {
    out[row * 3 + 0] = s[0] + lb[0];
    out[row * 3 + 1] = s[1] + lb[1];
    out[row * 3 + 2] = s[2] + lb[2];
  }
}

// ---------------------------------------------------------------------------
extern "C" void kernel_launch(void* const* d_in, const int* in_sizes, int n_in,
                              void* d_out, int out_size, void* d_ws, size_t ws_size,
                              hipStream_t stream) {
  const float* x     = (const float*)d_in[0];
  const float* ewihf = (const float*)d_in[1];
  const float* ewhhf = (const float*)d_in[2];
  const float* ebihf = (const float*)d_in[3];
  const float* ebhhf = (const float*)d_in[4];
  const float* ewihb = (const float*)d_in[5];
  const float* ewhhb = (const float*)d_in[6];
  const float* ebihb = (const float*)d_in[7];
  const float* ebhhb = (const float*)d_in[8];
  const float* dwih0 = (const float*)d_in[9];
  const float* dwhh0 = (const float*)d_in[10];
  const float* dbih0 = (const float*)d_in[11];
  const float* dbhh0 = (const float*)d_in[12];
  const float* dwih1 = (const float*)d_in[13];
  const float* dwhh1 = (const float*)d_in[14];
  const float* dbih1 = (const float*)d_in[15];
  const float* dbhh1 = (const float*)d_in[16];
  const float* lw    = (const float*)d_in[17];
  const float* lb    = (const float*)d_in[18];
  float* out = (float*)d_out;
  (void)in_sizes; (void)n_in; (void)out_size; (void)ws_size;

  char* wsb = (char*)d_ws;
  size_t off = 0;
  auto take = [&](size_t bytes) -> char* {
    char* p = wsb + off;
    off = (off + bytes + 255) & ~(size_t)255;
    return p;
  };
  u16*   xh    = (u16*)take(67108864ull * 2);    // x f16
  u16*   whx   = (u16*)take(2097152ull * 2);     // ew_ih f,b f16
  float* xp    = (float*)take(134217728ull * 4); // Xproj [2][512][128][1024] fp32
  u16*   wenc2 = (u16*)take(524288ull * 2);      // enc W_hh frags [2][8][64][64][8]
  u32*   dwf16 = (u32*)take(524288ull * 4);      // dec weights f16 pairs
  float* bias2 = (float*)take(2048 * 4);
  float* dbias = (float*)take(2048 * 4);
  float* h0b   = (float*)take(65536 * 4);
  float* h1b   = (float*)take(65536 * 4);
  float* inpb  = (float*)take(65536 * 4);
  float* cfb   = (float*)take(32768 * 4);
  float* cbb   = (float*)take(32768 * 4);
  float* hist  = (float*)take(2097152 * 4);
  int*   df    = (int*)take(256 * 4);

  init_k<<<256, 256, 0, stream>>>(inpb, df);
  convert_k<<<2048, 256, 0, stream>>>(x, ewihf, ewihb, ebihf, ebhhf, ebihb, ebhhb,
                                      dbih0, dbhh0, dbih1, dbhh1, xh, whx, bias2, dbias);
  convert_we2_k<<<2048, 256, 0, stream>>>(ewhhf, ewhhb, wenc2);
  convert_wd_k<<<2048, 256, 0, stream>>>(dwih0, dwhh0, dwih1, dwhh1, dwf16);
  xproj_gemm<<<8192, 256, 0, stream>>>(xh, whx, bias2, xp);
  encoder_k<<<16, 512, 0, stream>>>(wenc2, xp, h0b, h1b, cfb, cbb);
  decoder_k<<<256, 512, 0, stream>>>(dwf16, dbias, h0b, h1b, inpb, cfb, cbb, hist, df);
  logits_k<<<2048, 256, 0, stream>>>(hist, lw, lb, out);
}

// Round 8
// 3093.403 us; speedup vs baseline: 1.8670x; 1.8670x over previous
//
#include <hip/hip_runtime.h>
#include <hip/hip_bf16.h>
#include <math.h>

// ---------------------------------------------------------------------------
// Bi-LSTM encoder (final states only) -> 2-layer AR decoder (64 steps) -> vocab-3.
//   init_k        : zero decoder input buf / flags; sentinel the encoder h-ring
//   convert_k     : x, ew_ih_{f,b} -> f16; bias sums
//   convert_we3_k : enc W_hh -> gate-interleaved MFMA A-fragments (f16)
//   convert_wd_k  : dec [W_ih|W_hh] -> packed f16 pairs
//   xproj_gemm    : f16 MFMA GEMM -> Xproj[dir][t][b][1024] fp32 (+bias), dir1 reversed
//   encoder_k     : v8 — R6 depth-4 sentinel ring (proven) + register-local epilogue:
//                   gate-interleaved A-frags put all 4 gates of a cell in one lane's
//                   acc -> no red buffer, no bank conflicts, ONE barrier/step;
//                   xp prefetch after h-store (vmcnt no longer waits on HBM)
//   decoder_k     : persistent (L,bg,jg) blocks, f16 dot2, relaxed-atomic flag sync
//   logits_k      : h1 history @ lw^T + lb
// ---------------------------------------------------------------------------

typedef unsigned short u16;
typedef unsigned int u32;
typedef unsigned long long u64;
typedef _Float16 f16;
typedef f16 f16x8 __attribute__((ext_vector_type(8)));
typedef f16 f16x2 __attribute__((ext_vector_type(2)));
typedef u16 u16x8 __attribute__((ext_vector_type(8)));
typedef u32 u32x4 __attribute__((ext_vector_type(4)));
typedef float f32x4 __attribute__((ext_vector_type(4)));

__device__ __forceinline__ u16 f2h(float f) {
  return __builtin_bit_cast(unsigned short, (f16)f);
}
__device__ __forceinline__ u32 packf16(float a, float b) {
  return (u32)f2h(a) | ((u32)f2h(b) << 16);
}
__device__ __forceinline__ float dot2(u32 h, u32 w, float c) {
  return __builtin_amdgcn_fdot2(__builtin_bit_cast(f16x2, h),
                                __builtin_bit_cast(f16x2, w), c, false);
}
__device__ __forceinline__ u64 ald64(const u64* p) {
  return __hip_atomic_load(p, __ATOMIC_RELAXED, __HIP_MEMORY_SCOPE_AGENT);
}
__device__ __forceinline__ void ast64(u64* p, u64 v) {
  __hip_atomic_store(p, v, __ATOMIC_RELAXED, __HIP_MEMORY_SCOPE_AGENT);
}

#define SENT 0xFFFFFFFFFFFFFFFFull   // f16 NaN pair: unreachable for h in (-1,1)

// ---------------------------------------------------------------------------
__global__ __launch_bounds__(256) void init_k(float* inpb, u32* hglob, int* df) {
  int gid = blockIdx.x * 256 + threadIdx.x;   // grid 512*256 = 131072
  hglob[gid] = 0xFFFFFFFFu;                   // sentinel all 4 ring slots
  if (gid < 65536) inpb[gid] = 0.f;
  if (gid < 256) df[gid] = 0;
}

// ---------------------------------------------------------------------------
__global__ __launch_bounds__(256) void convert_k(
    const float* __restrict__ x,
    const float* __restrict__ wfm, const float* __restrict__ wbm,
    const float* __restrict__ bif, const float* __restrict__ bhf,
    const float* __restrict__ bib, const float* __restrict__ bhb,
    const float* __restrict__ dbi0, const float* __restrict__ dbh0,
    const float* __restrict__ dbi1, const float* __restrict__ dbh1,
    u16* __restrict__ xh, u16* __restrict__ wh,
    float* __restrict__ bias2, float* __restrict__ dbias) {
  const long NX = 67108864L, NW = 1048576L;
  long gid = (long)blockIdx.x * 256 + threadIdx.x;
  if (gid < 1024) {
    bias2[gid]        = bif[gid] + bhf[gid];
    bias2[1024 + gid] = bib[gid] + bhb[gid];
    dbias[gid]        = dbi0[gid] + dbh0[gid];
    dbias[1024 + gid] = dbi1[gid] + dbh1[gid];
  }
  long total4 = (NX + 2 * NW) >> 2;
  long stride = (long)gridDim.x * 256;
  for (long q = gid; q < total4; q += stride) {
    long i = q << 2;
    const float* src; u16* dst; long o;
    if (i < NX)            { src = x;   dst = xh;      o = i; }
    else if (i < NX + NW)  { src = wfm; dst = wh;      o = i - NX; }
    else                   { src = wbm; dst = wh + NW; o = i - NX - NW; }
    float4 v = *(const float4*)&src[o];
    dst[o + 0] = f2h(v.x); dst[o + 1] = f2h(v.y);
    dst[o + 2] = f2h(v.z); dst[o + 3] = f2h(v.w);
  }
}

// ---------------------------------------------------------------------------
// enc W_hh -> gate-interleaved A-fragments:
//   wenc3[d][cg][w][ks][lane][j] = W_hh_d[gcol][ks*32 + (lane>>4)*8 + j]
//   with ri = lane&15, gcol = (ri&3)*256 + cg*16 + w*4 + (ri>>2).
// Then D-row ri = lq*4+e held by lane (brow=lane&15, lq) gives gate e of
// cell (brow, col = cg*16 + w*4 + lq): epilogue fully register-local.
__global__ __launch_bounds__(256) void convert_we3_k(
    const float* __restrict__ whf, const float* __restrict__ whb,
    u16* __restrict__ wenc3) {
  int o = blockIdx.x * 256 + threadIdx.x;     // grid 2048*256 = 524288
  int j = o & 7, lane = (o >> 3) & 63, ks = (o >> 9) & 7;
  int w = (o >> 12) & 3, cg = (o >> 14) & 15, d = o >> 18;
  int ri = lane & 15;
  int gcol = (ri & 3) * 256 + cg * 16 + w * 4 + (ri >> 2);
  int k = ks * 32 + (lane >> 4) * 8 + j;
  const float* wsrc = d ? whb : whf;
  wenc3[o] = f2h(wsrc[gcol * 256 + k]);
}

// ---------------------------------------------------------------------------
// dec [W_ih|W_hh] -> packed f16 pairs: dwf16[L(2)][ks(16)][kp(16)][g(4)][c(256)]
__global__ __launch_bounds__(256) void convert_wd_k(
    const float* __restrict__ wi0, const float* __restrict__ wh0,
    const float* __restrict__ wi1, const float* __restrict__ wh1,
    u32* __restrict__ dwf16) {
  int i = blockIdx.x * 256 + threadIdx.x;     // grid 2048*256 = 524288
  int L = i >> 18, ks = (i >> 14) & 15, kp = (i >> 10) & 15;
  int g = (i >> 8) & 3, c = i & 255;
  int grow = g * 256 + c;
  int kk = (ks * 16 + kp) * 2;
  const float* wi = L ? wi1 : wi0;
  const float* wh = L ? wh1 : wh0;
  const float* s = (kk < 256) ? &wi[grow * 256 + kk] : &wh[grow * 256 + kk - 256];
  dwf16[i] = packf16(s[0], s[1]);
}

// ---------------------------------------------------------------------------
// Xproj GEMM (f16): C = X @ W^T + bias, 128x128 tiles, mfma_f32_16x16x32_f16.
__global__ __launch_bounds__(256) void xproj_gemm(
    const u16* __restrict__ xh, const u16* __restrict__ wh,
    const float* __restrict__ bias2, float* __restrict__ xp) {
  __shared__ u16 Al[128][40];
  __shared__ u16 Bl[128][40];
  int bid = blockIdx.x;
  int dir = bid >> 12, rem = bid & 4095, tb = rem >> 3, nb = rem & 7;
  int tsrc = dir ? (511 - tb) : tb;
  const u16* A  = xh + (long)tsrc * (128 * 1024);
  const u16* Bw = wh + (long)dir * (1024 * 1024) + (long)nb * (128 * 1024);
  float* C = xp + ((long)(dir * 512 + tb) * 128) * 1024 + nb * 128;
  const float* bias = bias2 + dir * 1024 + nb * 128;

  int tid = threadIdx.x, lane = tid & 63, wid = tid >> 6;
  int wr = wid >> 1, wc = wid & 1;
  int srow = tid >> 1, scol = (tid & 1) * 16;
  int fr = lane & 15, ko = lane >> 4;

  f32x4 acc[4][4] = {};
  for (int k0 = 0; k0 < 1024; k0 += 32) {
    u16x8 a0 = *(const u16x8*)&A[(long)srow * 1024 + k0 + scol];
    u16x8 a1 = *(const u16x8*)&A[(long)srow * 1024 + k0 + scol + 8];
    u16x8 b0 = *(const u16x8*)&Bw[(long)srow * 1024 + k0 + scol];
    u16x8 b1 = *(const u16x8*)&Bw[(long)srow * 1024 + k0 + scol + 8];
    __syncthreads();
    *(u16x8*)&Al[srow][scol]     = a0;
    *(u16x8*)&Al[srow][scol + 8] = a1;
    *(u16x8*)&Bl[srow][scol]     = b0;
    *(u16x8*)&Bl[srow][scol + 8] = b1;
    __syncthreads();
    f16x8 af[4], bf[4];
#pragma unroll
    for (int i = 0; i < 4; ++i)
      af[i] = __builtin_bit_cast(f16x8, *(const u16x8*)&Al[wr * 64 + i * 16 + fr][ko * 8]);
#pragma unroll
    for (int jf = 0; jf < 4; ++jf)
      bf[jf] = __builtin_bit_cast(f16x8, *(const u16x8*)&Bl[wc * 64 + jf * 16 + fr][ko * 8]);
#pragma unroll
    for (int i = 0; i < 4; ++i)
#pragma unroll
      for (int jf = 0; jf < 4; ++jf)
        acc[i][jf] = __builtin_amdgcn_mfma_f32_16x16x32_f16(af[i], bf[jf], acc[i][jf], 0, 0, 0);
  }
  int fq = lane >> 4;
#pragma unroll
  for (int i = 0; i < 4; ++i)
#pragma unroll
    for (int jf = 0; jf < 4; ++jf) {
      int col = wc * 64 + jf * 16 + fr;
      float bv = bias[col];
#pragma unroll
      for (int e = 0; e < 4; ++e) {
        int row = wr * 64 + i * 16 + fq * 4 + e;
        C[(long)row * 1024 + col] = acc[i][jf][e] + bv;
      }
    }
}

// ---------------------------------------------------------------------------
// Encoder v8: 256 blocks = d(2) x bg(8; 16 rows) x cg(16; 16 hcols), 256 thr.
// Wave w: A-frags = gate-interleaved W rows (8 frags = 32 VGPR); B = h_t from
// LDS (XOR-swizzled). After 8 MFMAs lane (brow,lq) holds all 4 gates of cell
// (brow, cg*16+w*4+lq) in acc[0..3] -> in-register LSTM cell, no red buffer.
// Depth-4 sentinel ring identical to R6 (proven): poll slot t&3, re-arm
// (t+2)&3, vmcnt(0), store (t+1)&3. ONE barrier/step. xp prefetch after store.
__global__ __launch_bounds__(256, 1) void encoder_k(
    const u16* __restrict__ wenc3, const float* __restrict__ xp,
    u32* hglob,
    float* h0b, float* h1b, float* cfb, float* cbb) {
  int b = blockIdx.x;
  int g16 = ((b >> 7) << 3) | (b & 7);        // group (d,bg): siblings share blockIdx%8
  int cg = (b >> 3) & 15;
  int d = g16 >> 3, bg = g16 & 7;
  int tid = threadIdx.x, lane = tid & 63, w = tid >> 6;
  int brow = lane & 15, lq = lane >> 4;
  int hswz = (brow & 7) << 4;

  __shared__ __align__(16) char hlds[2][8192];   // h [16 r][256 c] f16, swizzled, dbuf

  f16x8 wfr[8];                                  // 32 VGPRs, statically indexed
  {
    const u16* wb = wenc3 + (((long)d * 16 + cg) * 4 + w) * 4096 + lane * 8;
#pragma unroll
    for (int ks = 0; ks < 8; ++ks)
      wfr[ks] = __builtin_bit_cast(f16x8, *(const u16x8*)(wb + (long)ks * 512));
  }

  float c_state = 0.f;
  long xpbase = ((long)(d * 512) * 128 + bg * 16 + brow) * 1024 + cg * 16 + w * 4 + lq;
  float xpv[4];
#pragma unroll
  for (int g = 0; g < 4; ++g) xpv[g] = xp[xpbase + g * 256];

  u64* hg = (u64*)hglob;                         // [16 g][4 slot][16 r][64 u64]
  int r2 = tid >> 4, jj = tid & 15;
  long gbase0 = (long)g16 * 4096 + r2 * 64 + jj * 4;          // + slot*1024
  long mybase = (long)g16 * 4096 + brow * 64 + cg * 4 + w;    // storer (lq==0)
  int lbase = r2 * 512 + jj * 32, lxor = (r2 & 7) << 4;
  __syncthreads();

  for (int t = 0; t < 512; ++t) {
    if (t != 0) {
      // --- poll+gather h_t from slot t&3 ---
      long gb = gbase0 + (long)(t & 3) * 1024;
      u64 v0 = SENT, v1 = SENT, v2 = SENT, v3 = SENT;
      for (;;) {
        bool ok = true;
        if (v0 == SENT) { v0 = ald64(hg + gb + 0); ok &= (v0 != SENT); }
        if (v1 == SENT) { v1 = ald64(hg + gb + 1); ok &= (v1 != SENT); }
        if (v2 == SENT) { v2 = ald64(hg + gb + 2); ok &= (v2 != SENT); }
        if (v3 == SENT) { v3 = ald64(hg + gb + 3); ok &= (v3 != SENT); }
        if (ok) break;
      }
      // re-arm my word in the h_{t+2} slot (holds consumed h_{t-2})
      if (lq == 0)
        ast64(hg + mybase + (long)((t + 2) & 3) * 1024, SENT);
      char* hwr = hlds[t & 1];
      *(u64*)(hwr + ((lbase +  0) ^ lxor)) = v0;
      *(u64*)(hwr + ((lbase +  8) ^ lxor)) = v1;
      *(u64*)(hwr + ((lbase + 16) ^ lxor)) = v2;
      *(u64*)(hwr + ((lbase + 24) ^ lxor)) = v3;
    }
    __syncthreads();

    // --- 8 MFMAs: D[gcol(ri)][brow] accumulates; lane gets 4 gates in-reg ---
    f32x4 acc = {};
    if (t != 0) {
      const char* hrd = hlds[t & 1];
#pragma unroll
      for (int ks = 0; ks < 8; ++ks) {
        f16x8 hf = *(const f16x8*)(hrd + ((brow * 512 + ks * 64 + lq * 16) ^ hswz));
        acc = __builtin_amdgcn_mfma_f32_16x16x32_f16(wfr[ks], hf, acc, 0, 0, 0);
      }
    }

    // --- in-register LSTM cell (brow, cg*16 + w*4 + lq) ---
    float iv = 1.f / (1.f + expf(-(acc[0] + xpv[0])));
    float fv = 1.f / (1.f + expf(-(acc[1] + xpv[1])));
    float gg = tanhf(acc[2] + xpv[2]);
    float ov = 1.f / (1.f + expf(-(acc[3] + xpv[3])));
    c_state = fv * c_state + iv * gg;
    float hval = ov * tanhf(c_state);

    if (t < 511) {
      u16 hb = f2h(hval);
      u32 p1 = ((u32)__shfl_xor((int)(u32)hb, 16)) & 0xffffu;
      u32 pk = (u32)hb | (p1 << 16);                 // cols (w*4+0, w*4+1) on lq=0
      u32 hi = (u32)__shfl_xor((int)pk, 32);         // cols (w*4+2, w*4+3)
      // release: re-arm (and all prior VMEM) complete before data store
      asm volatile("s_waitcnt vmcnt(0)" ::: "memory");
      if (lq == 0)
        ast64(hg + mybase + (long)((t + 1) & 3) * 1024, (u64)pk | ((u64)hi << 32));
      // prefetch next xp AFTER the store: full step of latency cover,
      // and the next vmcnt(0) no longer serializes on it
      long xb2 = xpbase + (long)(t + 1) * 131072;
#pragma unroll
      for (int g = 0; g < 4; ++g) xpv[g] = xp[xb2 + g * 256];
    } else {
      int rowg = bg * 16 + brow, colg = cg * 16 + w * 4 + lq;
      (d ? h1b : h0b)[32768 + rowg * 256 + colg] = hval;  // parity-1 slot for decoder
      (d ? cbb : cfb)[rowg * 256 + colg] = c_state;
    }
  }
}

// ---------------------------------------------------------------------------
// Decoder (R2, proven): 256 blocks = L(2) x bg(16) x jg(8), 512 thr.
__global__ __launch_bounds__(512) void decoder_k(
    const u32* __restrict__ dwf16, const float* __restrict__ dbias,
    float* h0b, float* h1b, float* inpb,
    const float* __restrict__ cfb, const float* __restrict__ cbb,
    float* hist, int* df) {
  int bid = blockIdx.x;
  int L = bid >> 7, bg = (bid >> 3) & 15, jg = bid & 7;
  int tid = threadIdx.x;
  int j = tid & 31, ks = tid >> 5;

  u32 w2[4][16];
  {
    const u32* p = dwf16 + (long)(L * 16 + ks) * 16384 + jg * 32 + j;
#pragma unroll
    for (int kp = 0; kp < 16; ++kp)
#pragma unroll
      for (int g = 0; g < 4; ++g)
        w2[g][kp] = p[(kp * 4 + g) * 256];
  }

  __shared__ u32 xl[8][256];
  __shared__ float red[16][8][4][32];
  float c_state = 0.f;
  if (tid < 256)
    c_state = (L ? cbb : cfb)[(bg * 8 + (tid >> 5)) * 256 + jg * 32 + (tid & 31)];
  int srow = tid >> 6, sk8 = (tid & 63) * 8;

  for (int t = 0; t < 64; ++t) {
    if (tid < 16) {
      int p = tid & 7, which = tid >> 3;
      int need = (which == 0) ? ((L == 0) ? t : t + 1) : t;
      int* fp = &df[which * 128 + bg * 8 + p];
      while (__hip_atomic_load(fp, __ATOMIC_RELAXED, __HIP_MEMORY_SCOPE_AGENT) < need)
        __builtin_amdgcn_s_sleep(1);
    }
    __syncthreads();
    {
      const float* xsrc  = (L == 0) ? inpb + (t & 1) * 32768 : h0b + (t & 1) * 32768;
      const float* hsrc2 = (L == 0) ? h0b + ((t + 1) & 1) * 32768 : h1b + ((t + 1) & 1) * 32768;
      const float* s = (sk8 < 256) ? &xsrc[(bg * 8 + srow) * 256 + sk8]
                                   : &hsrc2[(bg * 8 + srow) * 256 + sk8 - 256];
      u32 pk[4];
#pragma unroll
      for (int q = 0; q < 4; ++q) {
        float v0 = __hip_atomic_load(&s[2 * q],     __ATOMIC_RELAXED, __HIP_MEMORY_SCOPE_AGENT);
        float v1 = __hip_atomic_load(&s[2 * q + 1], __ATOMIC_RELAXED, __HIP_MEMORY_SCOPE_AGENT);
        pk[q] = packf16(v0, v1);
      }
      *(u32x4*)&xl[srow][(tid & 63) * 4] = (u32x4){pk[0], pk[1], pk[2], pk[3]};
    }
    __syncthreads();

    float acc[8][4] = {};
#pragma unroll
    for (int r = 0; r < 8; ++r) {
#pragma unroll
      for (int kc = 0; kc < 4; ++kc) {
        const u32* hq = &xl[r][ks * 16 + kc * 4];
        u32 q0 = hq[0], q1 = hq[1], q2 = hq[2], q3 = hq[3];
#pragma unroll
        for (int g = 0; g < 4; ++g) {
          acc[r][g] = dot2(q0, w2[g][kc * 4 + 0], acc[r][g]);
          acc[r][g] = dot2(q1, w2[g][kc * 4 + 1], acc[r][g]);
          acc[r][g] = dot2(q2, w2[g][kc * 4 + 2], acc[r][g]);
          acc[r][g] = dot2(q3, w2[g][kc * 4 + 3], acc[r][g]);
        }
      }
    }
#pragma unroll
    for (int r = 0; r < 8; ++r)
#pragma unroll
      for (int g = 0; g < 4; ++g)
        red[ks][r][g][j] = acc[r][g];
    __syncthreads();

    if (tid < 256) {
      int re = tid >> 5, je = tid & 31;
      float gv[4];
#pragma unroll
      for (int g = 0; g < 4; ++g) {
        float sum = dbias[L * 1024 + g * 256 + jg * 32 + je];
#pragma unroll
        for (int p = 0; p < 16; ++p) sum += red[p][re][g][je];
        gv[g] = sum;
      }
      float iv = 1.f / (1.f + expf(-gv[0]));
      float fv = 1.f / (1.f + expf(-gv[1]));
      float gt = tanhf(gv[2]);
      float ov = 1.f / (1.f + expf(-gv[3]));
      c_state = fv * c_state + iv * gt;
      float hval = ov * tanhf(c_state);
      int rowg = bg * 8 + re, colg = jg * 32 + je;
      if (L == 0) {
        __hip_atomic_store(&h0b[(t & 1) * 32768 + rowg * 256 + colg], hval,
                           __ATOMIC_RELAXED, __HIP_MEMORY_SCOPE_AGENT);
      } else {
        __hip_atomic_store(&h1b[(t & 1) * 32768 + rowg * 256 + colg], hval,
                           __ATOMIC_RELAXED, __HIP_MEMORY_SCOPE_AGENT);
        __hip_atomic_store(&inpb[((t + 1) & 1) * 32768 + rowg * 256 + colg], hval,
                           __ATOMIC_RELAXED, __HIP_MEMORY_SCOPE_AGENT);
        hist[((long)t * 128 + rowg) * 256 + colg] = hval;
      }
    }
    asm volatile("s_waitcnt vmcnt(0)" ::: "memory");
    __syncthreads();
    if (tid == 0)
      __hip_atomic_store(&df[L * 128 + bg * 8 + jg], t + 1,
                         __ATOMIC_RELAXED, __HIP_MEMORY_SCOPE_AGENT);
  }
}

// ---------------------------------------------------------------------------
__global__ __launch_bounds__(256) void logits_k(
    const float* __restrict__ hist, const float* __restrict__ lw,
    const float* __restrict__ lb, float* __restrict__ out) {
  int widx = threadIdx.x >> 6, lane = threadIdx.x & 63;
  int row = blockIdx.x * 4 + widx;
  const float* h = hist + (long)row * 256;
  float4 hv = *(const float4*)&h[lane * 4];
  float s[3];
#pragma unroll
  for (int v = 0; v < 3; ++v) {
    float4 wv = *(const float4*)&lw[v * 256 + lane * 4];
    float p = hv.x * wv.x + hv.y * wv.y + hv.z * wv.z + hv.w * wv.w;
#pragma unroll
    for (int o = 32; o > 0; o >>= 1) p += __shfl_xor(p, o, 64);
    s[v] = p;
  }
  if (lane == 0) {
    out[row * 3 + 0] = s[0] + lb[0];
    out[row * 3 + 1] = s[1] + lb[1];
    out[row * 3 + 2] = s[2] + lb[2];
  }
}

// ---------------------------------------------------------------------------
extern "C" void kernel_launch(void* const* d_in, const int* in_sizes, int n_in,
                              void* d_out, int out_size, void* d_ws, size_t ws_size,
                              hipStream_t stream) {
  const float* x     = (const float*)d_in[0];
  const float* ewihf = (const float*)d_in[1];
  const float* ewhhf = (const float*)d_in[2];
  const float* ebihf = (const float*)d_in[3];
  const float* ebhhf = (const float*)d_in[4];
  const float* ewihb = (const float*)d_in[5];
  const float* ewhhb = (const float*)d_in[6];
  const float* ebihb = (const float*)d_in[7];
  const float* ebhhb = (const float*)d_in[8];
  const float* dwih0 = (const float*)d_in[9];
  const float* dwhh0 = (const float*)d_in[10];
  const float* dbih0 = (const float*)d_in[11];
  const float* dbhh0 = (const float*)d_in[12];
  const float* dwih1 = (const float*)d_in[13];
  const float* dwhh1 = (const float*)d_in[14];
  const float* dbih1 = (const float*)d_in[15];
  const float* dbhh1 = (const float*)d_in[16];
  const float* lw    = (const float*)d_in[17];
  const float* lb    = (const float*)d_in[18];
  float* out = (float*)d_out;
  (void)in_sizes; (void)n_in; (void)out_size; (void)ws_size;

  char* wsb = (char*)d_ws;
  size_t off = 0;
  auto take = [&](size_t bytes) -> char* {
    char* p = wsb + off;
    off = (off + bytes + 255) & ~(size_t)255;
    return p;
  };
  u16*   xh    = (u16*)take(67108864ull * 2);    // x f16
  u16*   whx   = (u16*)take(2097152ull * 2);     // ew_ih f,b f16
  float* xp    = (float*)take(134217728ull * 4); // Xproj [2][512][128][1024] fp32
  u16*   wenc3 = (u16*)take(524288ull * 2);      // enc W_hh gate-interleaved frags
  u32*   dwf16 = (u32*)take(524288ull * 4);      // dec weights f16 pairs
  float* bias2 = (float*)take(2048 * 4);
  float* dbias = (float*)take(2048 * 4);
  u32*   hglob = (u32*)take(131072ull * 4);      // enc h ring [16g][4 slot][16r][128]
  float* h0b   = (float*)take(65536 * 4);
  float* h1b   = (float*)take(65536 * 4);
  float* inpb  = (float*)take(65536 * 4);
  float* cfb   = (float*)take(32768 * 4);
  float* cbb   = (float*)take(32768 * 4);
  float* hist  = (float*)take(2097152 * 4);
  int*   df    = (int*)take(256 * 4);

  init_k<<<512, 256, 0, stream>>>(inpb, hglob, df);
  convert_k<<<2048, 256, 0, stream>>>(x, ewihf, ewihb, ebihf, ebhhf, ebihb, ebhhb,
                                      dbih0, dbhh0, dbih1, dbhh1, xh, whx, bias2, dbias);
  convert_we3_k<<<2048, 256, 0, stream>>>(ewhhf, ewhhb, wenc3);
  convert_wd_k<<<2048, 256, 0, stream>>>(dwih0, dwhh0, dwih1, dwhh1, dwf16);
  xproj_gemm<<<8192, 256, 0, stream>>>(xh, whx, bias2, xp);
  encoder_k<<<256, 256, 0, stream>>>(wenc3, xp, hglob, h0b, h1b, cfb, cbb);
  decoder_k<<<256, 512, 0, stream>>>(dwf16, dbias, h0b, h1b, inpb, cfb, cbb, hist, df);
  logits_k<<<2048, 256, 0, stream>>>(hist, lw, lb, out);
}

// Round 10
// 2884.000 us; speedup vs baseline: 2.0025x; 1.0726x over previous
//
#include <hip/hip_runtime.h>
#include <hip/hip_bf16.h>
#include <math.h>

// ---------------------------------------------------------------------------
// Bi-LSTM encoder (final states only) -> 2-layer AR decoder (64 steps) -> vocab-3.
//   init_k        : zero decoder input buf / flags; sentinel the encoder h-ring
//   convert_k     : x, ew_ih_{f,b} -> f16; bias sums
//   convert_we3_k : enc W_hh -> gate-interleaved MFMA A-fragments (f16)
//   convert_wd_k  : dec [W_ih|W_hh] -> packed f16 pairs
//   xproj_gemm    : f16 MFMA GEMM -> Xproj[dir][t][b][1024] fp32 (+bias), dir1 reversed
//   encoder_k     : v9b — depth-4 sentinel ring, fully coalesced exchange
//                   (512B store burst / 8KB coalesced gather, 4 u64 per thread),
//                   register-local epilogue via gate-interleaved A-frags
//   decoder_k     : persistent (L,bg,jg) blocks, f16 dot2, relaxed-atomic flag sync
//   logits_k      : h1 history @ lw^T + lb
// ---------------------------------------------------------------------------

typedef unsigned short u16;
typedef unsigned int u32;
typedef unsigned long long u64;
typedef _Float16 f16;
typedef f16 f16x8 __attribute__((ext_vector_type(8)));
typedef f16 f16x2 __attribute__((ext_vector_type(2)));
typedef u16 u16x8 __attribute__((ext_vector_type(8)));
typedef u32 u32x4 __attribute__((ext_vector_type(4)));
typedef float f32x4 __attribute__((ext_vector_type(4)));

__device__ __forceinline__ u16 f2h(float f) {
  return __builtin_bit_cast(unsigned short, (f16)f);
}
__device__ __forceinline__ u32 packf16(float a, float b) {
  return (u32)f2h(a) | ((u32)f2h(b) << 16);
}
__device__ __forceinline__ float dot2(u32 h, u32 w, float c) {
  return __builtin_amdgcn_fdot2(__builtin_bit_cast(f16x2, h),
                                __builtin_bit_cast(f16x2, w), c, false);
}
__device__ __forceinline__ u64 ald64(const u64* p) {
  return __hip_atomic_load(p, __ATOMIC_RELAXED, __HIP_MEMORY_SCOPE_AGENT);
}
__device__ __forceinline__ void ast64(u64* p, u64 v) {
  __hip_atomic_store(p, v, __ATOMIC_RELAXED, __HIP_MEMORY_SCOPE_AGENT);
}

#define SENT 0xFFFFFFFFFFFFFFFFull   // f16 NaN quad: unreachable for h in (-1,1)

// ---------------------------------------------------------------------------
__global__ __launch_bounds__(256) void init_k(float* inpb, u32* hglob, int* df) {
  int gid = blockIdx.x * 256 + threadIdx.x;   // grid 512*256 = 131072
  hglob[gid] = 0xFFFFFFFFu;                   // sentinel all 4 ring slots
  if (gid < 65536) inpb[gid] = 0.f;
  if (gid < 256) df[gid] = 0;
}

// ---------------------------------------------------------------------------
__global__ __launch_bounds__(256) void convert_k(
    const float* __restrict__ x,
    const float* __restrict__ wfm, const float* __restrict__ wbm,
    const float* __restrict__ bif, const float* __restrict__ bhf,
    const float* __restrict__ bib, const float* __restrict__ bhb,
    const float* __restrict__ dbi0, const float* __restrict__ dbh0,
    const float* __restrict__ dbi1, const float* __restrict__ dbh1,
    u16* __restrict__ xh, u16* __restrict__ wh,
    float* __restrict__ bias2, float* __restrict__ dbias) {
  const long NX = 67108864L, NW = 1048576L;
  long gid = (long)blockIdx.x * 256 + threadIdx.x;
  if (gid < 1024) {
    bias2[gid]        = bif[gid] + bhf[gid];
    bias2[1024 + gid] = bib[gid] + bhb[gid];
    dbias[gid]        = dbi0[gid] + dbh0[gid];
    dbias[1024 + gid] = dbi1[gid] + dbh1[gid];
  }
  long total4 = (NX + 2 * NW) >> 2;
  long stride = (long)gridDim.x * 256;
  for (long q = gid; q < total4; q += stride) {
    long i = q << 2;
    const float* src; u16* dst; long o;
    if (i < NX)            { src = x;   dst = xh;      o = i; }
    else if (i < NX + NW)  { src = wfm; dst = wh;      o = i - NX; }
    else                   { src = wbm; dst = wh + NW; o = i - NX - NW; }
    float4 v = *(const float4*)&src[o];
    dst[o + 0] = f2h(v.x); dst[o + 1] = f2h(v.y);
    dst[o + 2] = f2h(v.z); dst[o + 3] = f2h(v.w);
  }
}

// ---------------------------------------------------------------------------
// enc W_hh -> gate-interleaved A-fragments:
//   wenc3[d][cg][w][ks][lane][j] = W_hh_d[gcol][ks*32 + (lane>>4)*8 + j]
//   with ri = lane&15, gcol = (ri&3)*256 + cg*16 + w*4 + (ri>>2).
__global__ __launch_bounds__(256) void convert_we3_k(
    const float* __restrict__ whf, const float* __restrict__ whb,
    u16* __restrict__ wenc3) {
  int o = blockIdx.x * 256 + threadIdx.x;     // grid 2048*256 = 524288
  int j = o & 7, lane = (o >> 3) & 63, ks = (o >> 9) & 7;
  int w = (o >> 12) & 3, cg = (o >> 14) & 15, d = o >> 18;
  int ri = lane & 15;
  int gcol = (ri & 3) * 256 + cg * 16 + w * 4 + (ri >> 2);
  int k = ks * 32 + (lane >> 4) * 8 + j;
  const float* wsrc = d ? whb : whf;
  wenc3[o] = f2h(wsrc[gcol * 256 + k]);
}

// ---------------------------------------------------------------------------
// dec [W_ih|W_hh] -> packed f16 pairs: dwf16[L(2)][ks(16)][kp(16)][g(4)][c(256)]
__global__ __launch_bounds__(256) void convert_wd_k(
    const float* __restrict__ wi0, const float* __restrict__ wh0,
    const float* __restrict__ wi1, const float* __restrict__ wh1,
    u32* __restrict__ dwf16) {
  int i = blockIdx.x * 256 + threadIdx.x;     // grid 2048*256 = 524288
  int L = i >> 18, ks = (i >> 14) & 15, kp = (i >> 10) & 15;
  int g = (i >> 8) & 3, c = i & 255;
  int grow = g * 256 + c;
  int kk = (ks * 16 + kp) * 2;
  const float* wi = L ? wi1 : wi0;
  const float* wh = L ? wh1 : wh0;
  const float* s = (kk < 256) ? &wi[grow * 256 + kk] : &wh[grow * 256 + kk - 256];
  dwf16[i] = packf16(s[0], s[1]);
}

// ---------------------------------------------------------------------------
// Xproj GEMM (f16): C = X @ W^T + bias, 128x128 tiles, mfma_f32_16x16x32_f16.
__global__ __launch_bounds__(256) void xproj_gemm(
    const u16* __restrict__ xh, const u16* __restrict__ wh,
    const float* __restrict__ bias2, float* __restrict__ xp) {
  __shared__ u16 Al[128][40];
  __shared__ u16 Bl[128][40];
  int bid = blockIdx.x;
  int dir = bid >> 12, rem = bid & 4095, tb = rem >> 3, nb = rem & 7;
  int tsrc = dir ? (511 - tb) : tb;
  const u16* A  = xh + (long)tsrc * (128 * 1024);
  const u16* Bw = wh + (long)dir * (1024 * 1024) + (long)nb * (128 * 1024);
  float* C = xp + ((long)(dir * 512 + tb) * 128) * 1024 + nb * 128;
  const float* bias = bias2 + dir * 1024 + nb * 128;

  int tid = threadIdx.x, lane = tid & 63, wid = tid >> 6;
  int wr = wid >> 1, wc = wid & 1;
  int srow = tid >> 1, scol = (tid & 1) * 16;
  int fr = lane & 15, ko = lane >> 4;

  f32x4 acc[4][4] = {};
  for (int k0 = 0; k0 < 1024; k0 += 32) {
    u16x8 a0 = *(const u16x8*)&A[(long)srow * 1024 + k0 + scol];
    u16x8 a1 = *(const u16x8*)&A[(long)srow * 1024 + k0 + scol + 8];
    u16x8 b0 = *(const u16x8*)&Bw[(long)srow * 1024 + k0 + scol];
    u16x8 b1 = *(const u16x8*)&Bw[(long)srow * 1024 + k0 + scol + 8];
    __syncthreads();
    *(u16x8*)&Al[srow][scol]     = a0;
    *(u16x8*)&Al[srow][scol + 8] = a1;
    *(u16x8*)&Bl[srow][scol]     = b0;
    *(u16x8*)&Bl[srow][scol + 8] = b1;
    __syncthreads();
    f16x8 af[4], bf[4];
#pragma unroll
    for (int i = 0; i < 4; ++i)
      af[i] = __builtin_bit_cast(f16x8, *(const u16x8*)&Al[wr * 64 + i * 16 + fr][ko * 8]);
#pragma unroll
    for (int jf = 0; jf < 4; ++jf)
      bf[jf] = __builtin_bit_cast(f16x8, *(const u16x8*)&Bl[wc * 64 + jf * 16 + fr][ko * 8]);
#pragma unroll
    for (int i = 0; i < 4; ++i)
#pragma unroll
      for (int jf = 0; jf < 4; ++jf)
        acc[i][jf] = __builtin_amdgcn_mfma_f32_16x16x32_f16(af[i], bf[jf], acc[i][jf], 0, 0, 0);
  }
  int fq = lane >> 4;
#pragma unroll
  for (int i = 0; i < 4; ++i)
#pragma unroll
    for (int jf = 0; jf < 4; ++jf) {
      int col = wc * 64 + jf * 16 + fr;
      float bv = bias[col];
#pragma unroll
      for (int e = 0; e < 4; ++e) {
        int row = wr * 64 + i * 16 + fq * 4 + e;
        C[(long)row * 1024 + col] = acc[i][jf][e] + bv;
      }
    }
}

// ---------------------------------------------------------------------------
// Encoder v9b: 256 blocks = d(2) x bg(8; 16 rows) x cg(16; 16 hcols), 256 thr.
// Ring layout [g16][slot4][cg16][brow16][qcol4] u64:
//   store  : 64 threads write u64 at base+cg*64+tid -> ONE 512B contiguous burst
//   re-arm : same threads, same addresses, slot+2
//   gather : thread tid reads 4 u64 at base+4*tid -> 8KB fully coalesced
//            (tid = gcg*16+gbrow -> row gbrow, cols gcg*16..+15 -> 32B LDS write)
// MFMA: gate-interleaved A-frags (32 VGPR), lane gets all 4 gates of one cell
// in-register (no reduction buffer). 2 barriers/step.
// Protocol: poll slot t&3 (data==flag), re-arm (t+2)&3, vmcnt(0), store (t+1)&3.
__global__ __launch_bounds__(256, 1) void encoder_k(
    const u16* __restrict__ wenc3, const float* __restrict__ xp,
    u32* hglob,
    float* h0b, float* h1b, float* cfb, float* cbb) {
  int b = blockIdx.x;
  int g16 = ((b >> 7) << 3) | (b & 7);        // group (d,bg): siblings share blockIdx%8
  int cg = (b >> 3) & 15;
  int d = g16 >> 3, bg = g16 & 7;
  int tid = threadIdx.x, lane = tid & 63, w = tid >> 6;
  int brow = lane & 15, lq = lane >> 4;
  int hswz = (brow & 7) << 4;

  __shared__ __align__(16) char hlds[2][8192];   // h [16 r][256 c] f16, swizzled, dbuf
  __shared__ __align__(16) u16 hstage[16][16];   // h_{t+1} stage [brow][col-in-block]

  f16x8 wfr[8];                                  // 32 VGPRs, statically indexed
  {
    const u16* wb = wenc3 + (((long)d * 16 + cg) * 4 + w) * 4096 + lane * 8;
#pragma unroll
    for (int ks = 0; ks < 8; ++ks)
      wfr[ks] = __builtin_bit_cast(f16x8, *(const u16x8*)(wb + (long)ks * 512));
  }

  float c_state = 0.f;
  long xpbase = ((long)(d * 512) * 128 + bg * 16 + brow) * 1024 + cg * 16 + w * 4 + lq;
  float xpv[4];
#pragma unroll
  for (int g = 0; g < 4; ++g) xpv[g] = xp[xpbase + g * 256];

  u64* hg = (u64*)hglob;                         // [16 g][4 slot][1024 u64]
  long ringbase = (long)g16 * 4096;
  // gather decode: thread tid <-> u64s 4*tid..4*tid+3: gcg=tid>>4, gbrow=tid&15
  int gcg = tid >> 4, gbrow = tid & 15;
  int gldsbase = gbrow * 512 + gcg * 32;
  int gswz = (gbrow & 7) << 4;
  __syncthreads();

  for (int t = 0; t < 512; ++t) {
    if (t != 0) {
      // --- poll+gather h_t from slot t&3 (coalesced: 4 u64 at base+4*tid) ---
      const long gb = ringbase + (long)(t & 3) * 1024 + 4 * tid;
      u64 v0 = SENT, v1 = SENT, v2 = SENT, v3 = SENT;
      for (;;) {
        bool ok = true;
        if (v0 == SENT) { v0 = ald64(hg + gb + 0); ok &= (v0 != SENT); }
        if (v1 == SENT) { v1 = ald64(hg + gb + 1); ok &= (v1 != SENT); }
        if (v2 == SENT) { v2 = ald64(hg + gb + 2); ok &= (v2 != SENT); }
        if (v3 == SENT) { v3 = ald64(hg + gb + 3); ok &= (v3 != SENT); }
        if (ok) break;
      }
      // re-arm my store word in the h_{t+2} slot (holds consumed h_{t-2})
      if (tid < 64)
        ast64(hg + ringbase + (long)((t + 2) & 3) * 1024 + cg * 64 + tid, SENT);
      // h_t image -> LDS (swizzled row-major): 32B = two b128 writes
      char* hwr = hlds[t & 1];
      *(u32x4*)(hwr + (gldsbase ^ gswz)) =
          (u32x4){ (u32)v0, (u32)(v0 >> 32), (u32)v1, (u32)(v1 >> 32) };
      *(u32x4*)(hwr + ((gldsbase + 16) ^ gswz)) =
          (u32x4){ (u32)v2, (u32)(v2 >> 32), (u32)v3, (u32)(v3 >> 32) };
    }
    __syncthreads();

    // --- 8 MFMAs (2 acc chains): D[gcol(ri)][brow]; lane gets 4 gates in-reg ---
    f32x4 acc0 = {}, acc1 = {};
    if (t != 0) {
      const char* hrd = hlds[t & 1];
#pragma unroll
      for (int ks = 0; ks < 8; ++ks) {
        f16x8 hf = *(const f16x8*)(hrd + ((brow * 512 + ks * 64 + lq * 16) ^ hswz));
        if (ks & 1) acc1 = __builtin_amdgcn_mfma_f32_16x16x32_f16(wfr[ks], hf, acc1, 0, 0, 0);
        else        acc0 = __builtin_amdgcn_mfma_f32_16x16x32_f16(wfr[ks], hf, acc0, 0, 0, 0);
      }
    }

    // --- in-register LSTM cell (brow, cg*16 + w*4 + lq) ---
    float iv = 1.f / (1.f + expf(-(acc0[0] + acc1[0] + xpv[0])));
    float fv = 1.f / (1.f + expf(-(acc0[1] + acc1[1] + xpv[1])));
    float gg = tanhf(acc0[2] + acc1[2] + xpv[2]);
    float ov = 1.f / (1.f + expf(-(acc0[3] + acc1[3] + xpv[3])));
    c_state = fv * c_state + iv * gg;
    float hval = ov * tanhf(c_state);

    if (t < 511) {
      hstage[brow][w * 4 + lq] = f2h(hval);   // stage for coalesced store
      __syncthreads();
      // release: re-arm (and all prior VMEM) complete before data store
      asm volatile("s_waitcnt vmcnt(0)" ::: "memory");
      if (tid < 64) {
        u64 v = *(const u64*)&hstage[tid >> 2][(tid & 3) * 4];
        ast64(hg + ringbase + (long)((t + 1) & 3) * 1024 + cg * 64 + tid, v);
      }
      // prefetch next xp AFTER the store (full-step latency cover)
      long xb2 = xpbase + (long)(t + 1) * 131072;
#pragma unroll
      for (int g = 0; g < 4; ++g) xpv[g] = xp[xb2 + g * 256];
    } else {
      int rowg = bg * 16 + brow, colg = cg * 16 + w * 4 + lq;
      (d ? h1b : h0b)[32768 + rowg * 256 + colg] = hval;  // parity-1 slot for decoder
      (d ? cbb : cfb)[rowg * 256 + colg] = c_state;
    }
  }
}

// ---------------------------------------------------------------------------
// Decoder (R2, proven): 256 blocks = L(2) x bg(16) x jg(8), 512 thr.
__global__ __launch_bounds__(512) void decoder_k(
    const u32* __restrict__ dwf16, const float* __restrict__ dbias,
    float* h0b, float* h1b, float* inpb,
    const float* __restrict__ cfb, const float* __restrict__ cbb,
    float* hist, int* df) {
  int bid = blockIdx.x;
  int L = bid >> 7, bg = (bid >> 3) & 15, jg = bid & 7;
  int tid = threadIdx.x;
  int j = tid & 31, ks = tid >> 5;

  u32 w2[4][16];
  {
    const u32* p = dwf16 + (long)(L * 16 + ks) * 16384 + jg * 32 + j;
#pragma unroll
    for (int kp = 0; kp < 16; ++kp)
#pragma unroll
      for (int g = 0; g < 4; ++g)
        w2[g][kp] = p[(kp * 4 + g) * 256];
  }

  __shared__ u32 xl[8][256];
  __shared__ float red[16][8][4][32];
  float c_state = 0.f;
  if (tid < 256)
    c_state = (L ? cbb : cfb)[(bg * 8 + (tid >> 5)) * 256 + jg * 32 + (tid & 31)];
  int srow = tid >> 6, sk8 = (tid & 63) * 8;

  for (int t = 0; t < 64; ++t) {
    if (tid < 16) {
      int p = tid & 7, which = tid >> 3;
      int need = (which == 0) ? ((L == 0) ? t : t + 1) : t;
      int* fp = &df[which * 128 + bg * 8 + p];
      while (__hip_atomic_load(fp, __ATOMIC_RELAXED, __HIP_MEMORY_SCOPE_AGENT) < need)
        __builtin_amdgcn_s_sleep(1);
    }
    __syncthreads();
    {
      const float* xsrc  = (L == 0) ? inpb + (t & 1) * 32768 : h0b + (t & 1) * 32768;
      const float* hsrc2 = (L == 0) ? h0b + ((t + 1) & 1) * 32768 : h1b + ((t + 1) & 1) * 32768;
      const float* s = (sk8 < 256) ? &xsrc[(bg * 8 + srow) * 256 + sk8]
                                   : &hsrc2[(bg * 8 + srow) * 256 + sk8 - 256];
      u32 pk[4];
#pragma unroll
      for (int q = 0; q < 4; ++q) {
        float v0 = __hip_atomic_load(&s[2 * q],     __ATOMIC_RELAXED, __HIP_MEMORY_SCOPE_AGENT);
        float v1 = __hip_atomic_load(&s[2 * q + 1], __ATOMIC_RELAXED, __HIP_MEMORY_SCOPE_AGENT);
        pk[q] = packf16(v0, v1);
      }
      *(u32x4*)&xl[srow][(tid & 63) * 4] = (u32x4){pk[0], pk[1], pk[2], pk[3]};
    }
    __syncthreads();

    float acc[8][4] = {};
#pragma unroll
    for (int r = 0; r < 8; ++r) {
#pragma unroll
      for (int kc = 0; kc < 4; ++kc) {
        const u32* hq = &xl[r][ks * 16 + kc * 4];
        u32 q0 = hq[0], q1 = hq[1], q2 = hq[2], q3 = hq[3];
#pragma unroll
        for (int g = 0; g < 4; ++g) {
          acc[r][g] = dot2(q0, w2[g][kc * 4 + 0], acc[r][g]);
          acc[r][g] = dot2(q1, w2[g][kc * 4 + 1], acc[r][g]);
          acc[r][g] = dot2(q2, w2[g][kc * 4 + 2], acc[r][g]);
          acc[r][g] = dot2(q3, w2[g][kc * 4 + 3], acc[r][g]);
        }
      }
    }
#pragma unroll
    for (int r = 0; r < 8; ++r)
#pragma unroll
      for (int g = 0; g < 4; ++g)
        red[ks][r][g][j] = acc[r][g];
    __syncthreads();

    if (tid < 256) {
      int re = tid >> 5, je = tid & 31;
      float gv[4];
#pragma unroll
      for (int g = 0; g < 4; ++g) {
        float sum = dbias[L * 1024 + g * 256 + jg * 32 + je];
#pragma unroll
        for (int p = 0; p < 16; ++p) sum += red[p][re][g][je];
        gv[g] = sum;
      }
      float iv = 1.f / (1.f + expf(-gv[0]));
      float fv = 1.f / (1.f + expf(-gv[1]));
      float gt = tanhf(gv[2]);
      float ov = 1.f / (1.f + expf(-gv[3]));
      c_state = fv * c_state + iv * gt;
      float hval = ov * tanhf(c_state);
      int rowg = bg * 8 + re, colg = jg * 32 + je;
      if (L == 0) {
        __hip_atomic_store(&h0b[(t & 1) * 32768 + rowg * 256 + colg], hval,
                           __ATOMIC_RELAXED, __HIP_MEMORY_SCOPE_AGENT);
      } else {
        __hip_atomic_store(&h1b[(t & 1) * 32768 + rowg * 256 + colg], hval,
                           __ATOMIC_RELAXED, __HIP_MEMORY_SCOPE_AGENT);
        __hip_atomic_store(&inpb[((t + 1) & 1) * 32768 + rowg * 256 + colg], hval,
                           __ATOMIC_RELAXED, __HIP_MEMORY_SCOPE_AGENT);
        hist[((long)t * 128 + rowg) * 256 + colg] = hval;
      }
    }
    asm volatile("s_waitcnt vmcnt(0)" ::: "memory");
    __syncthreads();
    if (tid == 0)
      __hip_atomic_store(&df[L * 128 + bg * 8 + jg], t + 1,
                         __ATOMIC_RELAXED, __HIP_MEMORY_SCOPE_AGENT);
  }
}

// ---------------------------------------------------------------------------
__global__ __launch_bounds__(256) void logits_k(
    const float* __restrict__ hist, const float* __restrict__ lw,
    const float* __restrict__ lb, float* __restrict__ out) {
  int widx = threadIdx.x >> 6, lane = threadIdx.x & 63;
  int row = blockIdx.x * 4 + widx;
  const float* h = hist + (long)row * 256;
  float4 hv = *(const float4*)&h[lane * 4];
  float s[3];
#pragma unroll
  for (int v = 0; v < 3; ++v) {
    float4 wv = *(const float4*)&lw[v * 256 + lane * 4];
    float p = hv.x * wv.x + hv.y * wv.y + hv.z * wv.z + hv.w * wv.w;
#pragma unroll
    for (int o = 32; o > 0; o >>= 1) p += __shfl_xor(p, o, 64);
    s[v] = p;
  }
  if (lane == 0) {
    out[row * 3 + 0] = s[0] + lb[0];
    out[row * 3 + 1] = s[1] + lb[1];
    out[row * 3 + 2] = s[2] + lb[2];
  }
}

// ---------------------------------------------------------------------------
extern "C" void kernel_launch(void* const* d_in, const int* in_sizes, int n_in,
                              void* d_out, int out_size, void* d_ws, size_t ws_size,
                              hipStream_t stream) {
  const float* x     = (const float*)d_in[0];
  const float* ewihf = (const float*)d_in[1];
  const float* ewhhf = (const float*)d_in[2];
  const float* ebihf = (const float*)d_in[3];
  const float* ebhhf = (const float*)d_in[4];
  const float* ewihb = (const float*)d_in[5];
  const float* ewhhb = (const float*)d_in[6];
  const float* ebihb = (const float*)d_in[7];
  const float* ebhhb = (const float*)d_in[8];
  const float* dwih0 = (const float*)d_in[9];
  const float* dwhh0 = (const float*)d_in[10];
  const float* dbih0 = (const float*)d_in[11];
  const float* dbhh0 = (const float*)d_in[12];
  const float* dwih1 = (const float*)d_in[13];
  const float* dwhh1 = (const float*)d_in[14];
  const float* dbih1 = (const float*)d_in[15];
  const float* dbhh1 = (const float*)d_in[16];
  const float* lw    = (const float*)d_in[17];
  const float* lb    = (const float*)d_in[18];
  float* out = (float*)d_out;
  (void)in_sizes; (void)n_in; (void)out_size; (void)ws_size;

  char* wsb = (char*)d_ws;
  size_t off = 0;
  auto take = [&](size_t bytes) -> char* {
    char* p = wsb + off;
    off = (off + bytes + 255) & ~(size_t)255;
    return p;
  };
  u16*   xh    = (u16*)take(67108864ull * 2);    // x f16
  u16*   whx   = (u16*)take(2097152ull * 2);     // ew_ih f,b f16
  float* xp    = (float*)take(134217728ull * 4); // Xproj [2][512][128][1024] fp32
  u16*   wenc3 = (u16*)take(524288ull * 2);      // enc W_hh gate-interleaved frags
  u32*   dwf16 = (u32*)take(524288ull * 4);      // dec weights f16 pairs
  float* bias2 = (float*)take(2048 * 4);
  float* dbias = (float*)take(2048 * 4);
  u32*   hglob = (u32*)take(131072ull * 4);      // enc h ring [16g][4 slot][1024 u64]
  float* h0b   = (float*)take(65536 * 4);
  float* h1b   = (float*)take(65536 * 4);
  float* inpb  = (float*)take(65536 * 4);
  float* cfb   = (float*)take(32768 * 4);
  float* cbb   = (float*)take(32768 * 4);
  float* hist  = (float*)take(2097152 * 4);
  int*   df    = (int*)take(256 * 4);

  init_k<<<512, 256, 0, stream>>>(inpb, hglob, df);
  convert_k<<<2048, 256, 0, stream>>>(x, ewihf, ewihb, ebihf, ebhhf, ebihb, ebhhb,
                                      dbih0, dbhh0, dbih1, dbhh1, xh, whx, bias2, dbias);
  convert_we3_k<<<2048, 256, 0, stream>>>(ewhhf, ewhhb, wenc3);
  convert_wd_k<<<2048, 256, 0, stream>>>(dwih0, dwhh0, dwih1, dwhh1, dwf16);
  xproj_gemm<<<8192, 256, 0, stream>>>(xh, whx, bias2, xp);
  encoder_k<<<256, 256, 0, stream>>>(wenc3, xp, hglob, h0b, h1b, cfb, cbb);
  decoder_k<<<256, 512, 0, stream>>>(dwf16, dbias, h0b, h1b, inpb, cfb, cbb, hist, df);
  logits_k<<<2048, 256, 0, stream>>>(hist, lw, lb, out);
}

// Round 12
// 2092.124 us; speedup vs baseline: 2.7605x; 1.3785x over previous
//
#include <hip/hip_runtime.h>
#include <hip/hip_bf16.h>
#include <math.h>

// ---------------------------------------------------------------------------
// Bi-LSTM encoder (final states only) -> 2-layer AR decoder (64 steps) -> vocab-3.
//   init_k         : sentinel encoder h-ring + decoder rings r0/r1
//   convert_k      : x, ew_ih_{f,b} -> f16; bias sums
//   convert_we3_k  : enc W_hh -> gate-interleaved MFMA A-fragments (f16)
//   convert_wdec_k : dec [W_ih|W_hh] both layers -> gate-interleaved A-frags (f16)
//   xproj_gemm     : f16 MFMA GEMM -> Xproj[dir][t][b][1024] fp32 (+bias), dir1 reversed
//   encoder_k      : v9b (R10-proven) — depth-4 sentinel ring, coalesced exchange,
//                    register-local epilogue
//   decoder_k      : v3b — 128 blocks own 16 cols of BOTH layers (128 VGPR frags),
//                    two sentinel-ring exchanges per step; t=0 L0 input = zeros
//                    (reference inp0) -> skip hB MFMAs at t=0
//   logits_k       : h1 history @ lw^T + lb
// ---------------------------------------------------------------------------

typedef unsigned short u16;
typedef unsigned int u32;
typedef unsigned long long u64;
typedef _Float16 f16;
typedef f16 f16x8 __attribute__((ext_vector_type(8)));
typedef u16 u16x8 __attribute__((ext_vector_type(8)));
typedef u32 u32x4 __attribute__((ext_vector_type(4)));
typedef float f32x4 __attribute__((ext_vector_type(4)));

__device__ __forceinline__ u16 f2h(float f) {
  return __builtin_bit_cast(unsigned short, (f16)f);
}
__device__ __forceinline__ float h2f(u16 h) {
  return (float)__builtin_bit_cast(f16, h);
}
__device__ __forceinline__ u32 packf16(float a, float b) {
  return (u32)f2h(a) | ((u32)f2h(b) << 16);
}
__device__ __forceinline__ u64 ald64(const u64* p) {
  return __hip_atomic_load(p, __ATOMIC_RELAXED, __HIP_MEMORY_SCOPE_AGENT);
}
__device__ __forceinline__ void ast64(u64* p, u64 v) {
  __hip_atomic_store(p, v, __ATOMIC_RELAXED, __HIP_MEMORY_SCOPE_AGENT);
}

#define SENT 0xFFFFFFFFFFFFFFFFull   // f16 NaN quad: unreachable for h in (-1,1)

// ---------------------------------------------------------------------------
__global__ __launch_bounds__(256) void init_k(u32* hglob, u32* r0, u32* r1) {
  int gid = blockIdx.x * 256 + threadIdx.x;   // grid 1024*256 = 262144
  if (gid < 131072)       hglob[gid] = 0xFFFFFFFFu;
  else if (gid < 196608)  r0[gid - 131072] = 0xFFFFFFFFu;
  else                    r1[gid - 196608] = 0xFFFFFFFFu;
}

// ---------------------------------------------------------------------------
__global__ __launch_bounds__(256) void convert_k(
    const float* __restrict__ x,
    const float* __restrict__ wfm, const float* __restrict__ wbm,
    const float* __restrict__ bif, const float* __restrict__ bhf,
    const float* __restrict__ bib, const float* __restrict__ bhb,
    const float* __restrict__ dbi0, const float* __restrict__ dbh0,
    const float* __restrict__ dbi1, const float* __restrict__ dbh1,
    u16* __restrict__ xh, u16* __restrict__ wh,
    float* __restrict__ bias2, float* __restrict__ dbias) {
  const long NX = 67108864L, NW = 1048576L;
  long gid = (long)blockIdx.x * 256 + threadIdx.x;
  if (gid < 1024) {
    bias2[gid]        = bif[gid] + bhf[gid];
    bias2[1024 + gid] = bib[gid] + bhb[gid];
    dbias[gid]        = dbi0[gid] + dbh0[gid];
    dbias[1024 + gid] = dbi1[gid] + dbh1[gid];
  }
  long total4 = (NX + 2 * NW) >> 2;
  long stride = (long)gridDim.x * 256;
  for (long q = gid; q < total4; q += stride) {
    long i = q << 2;
    const float* src; u16* dst; long o;
    if (i < NX)            { src = x;   dst = xh;      o = i; }
    else if (i < NX + NW)  { src = wfm; dst = wh;      o = i - NX; }
    else                   { src = wbm; dst = wh + NW; o = i - NX - NW; }
    float4 v = *(const float4*)&src[o];
    dst[o + 0] = f2h(v.x); dst[o + 1] = f2h(v.y);
    dst[o + 2] = f2h(v.z); dst[o + 3] = f2h(v.w);
  }
}

// ---------------------------------------------------------------------------
// enc W_hh -> gate-interleaved A-fragments:
//   wenc3[d][cg][w][ks][lane][j] = W_hh_d[gcol][ks*32 + (lane>>4)*8 + j]
//   with ri = lane&15, gcol = (ri&3)*256 + cg*16 + w*4 + (ri>>2).
__global__ __launch_bounds__(256) void convert_we3_k(
    const float* __restrict__ whf, const float* __restrict__ whb,
    u16* __restrict__ wenc3) {
  int o = blockIdx.x * 256 + threadIdx.x;     // grid 2048*256 = 524288
  int j = o & 7, lane = (o >> 3) & 63, ks = (o >> 9) & 7;
  int w = (o >> 12) & 3, cg = (o >> 14) & 15, d = o >> 18;
  int ri = lane & 15;
  int gcol = (ri & 3) * 256 + cg * 16 + w * 4 + (ri >> 2);
  int k = ks * 32 + (lane >> 4) * 8 + j;
  const float* wsrc = d ? whb : whf;
  wenc3[o] = f2h(wsrc[gcol * 256 + k]);
}

// ---------------------------------------------------------------------------
// dec [W_ih|W_hh] (K=512) both layers -> gate-interleaved A-fragments:
//   wdec[L][cg][w][ks16][lane][j] = Wcat_L[gcol][ks*32 + (lane>>4)*8 + j]
//   gcol = (ri&3)*256 + cg*16 + w*4 + (ri>>2), ri = lane&15;
//   Wcat row r, k: k<256 -> w_ih[r][k], else w_hh[r][k-256].
__global__ __launch_bounds__(256) void convert_wdec_k(
    const float* __restrict__ wi0, const float* __restrict__ wh0,
    const float* __restrict__ wi1, const float* __restrict__ wh1,
    u16* __restrict__ wdec) {
  int o = blockIdx.x * 256 + threadIdx.x;     // grid 4096*256 = 1048576
  int j = o & 7, lane = (o >> 3) & 63, ks = (o >> 9) & 15;
  int w = (o >> 13) & 3, cg = (o >> 15) & 15, L = o >> 19;
  int ri = lane & 15;
  int row = (ri & 3) * 256 + cg * 16 + w * 4 + (ri >> 2);
  int k = ks * 32 + (lane >> 4) * 8 + j;
  const float* wi = L ? wi1 : wi0;
  const float* wh = L ? wh1 : wh0;
  float v = (k < 256) ? wi[row * 256 + k] : wh[row * 256 + k - 256];
  wdec[o] = f2h(v);
}

// ---------------------------------------------------------------------------
// Xproj GEMM (f16): C = X @ W^T + bias, 128x128 tiles, mfma_f32_16x16x32_f16.
__global__ __launch_bounds__(256) void xproj_gemm(
    const u16* __restrict__ xh, const u16* __restrict__ wh,
    const float* __restrict__ bias2, float* __restrict__ xp) {
  __shared__ u16 Al[128][40];
  __shared__ u16 Bl[128][40];
  int bid = blockIdx.x;
  int dir = bid >> 12, rem = bid & 4095, tb = rem >> 3, nb = rem & 7;
  int tsrc = dir ? (511 - tb) : tb;
  const u16* A  = xh + (long)tsrc * (128 * 1024);
  const u16* Bw = wh + (long)dir * (1024 * 1024) + (long)nb * (128 * 1024);
  float* C = xp + ((long)(dir * 512 + tb) * 128) * 1024 + nb * 128;
  const float* bias = bias2 + dir * 1024 + nb * 128;

  int tid = threadIdx.x, lane = tid & 63, wid = tid >> 6;
  int wr = wid >> 1, wc = wid & 1;
  int srow = tid >> 1, scol = (tid & 1) * 16;
  int fr = lane & 15, ko = lane >> 4;

  f32x4 acc[4][4] = {};
  for (int k0 = 0; k0 < 1024; k0 += 32) {
    u16x8 a0 = *(const u16x8*)&A[(long)srow * 1024 + k0 + scol];
    u16x8 a1 = *(const u16x8*)&A[(long)srow * 1024 + k0 + scol + 8];
    u16x8 b0 = *(const u16x8*)&Bw[(long)srow * 1024 + k0 + scol];
    u16x8 b1 = *(const u16x8*)&Bw[(long)srow * 1024 + k0 + scol + 8];
    __syncthreads();
    *(u16x8*)&Al[srow][scol]     = a0;
    *(u16x8*)&Al[srow][scol + 8] = a1;
    *(u16x8*)&Bl[srow][scol]     = b0;
    *(u16x8*)&Bl[srow][scol + 8] = b1;
    __syncthreads();
    f16x8 af[4], bf[4];
#pragma unroll
    for (int i = 0; i < 4; ++i)
      af[i] = __builtin_bit_cast(f16x8, *(const u16x8*)&Al[wr * 64 + i * 16 + fr][ko * 8]);
#pragma unroll
    for (int jf = 0; jf < 4; ++jf)
      bf[jf] = __builtin_bit_cast(f16x8, *(const u16x8*)&Bl[wc * 64 + jf * 16 + fr][ko * 8]);
#pragma unroll
    for (int i = 0; i < 4; ++i)
#pragma unroll
      for (int jf = 0; jf < 4; ++jf)
        acc[i][jf] = __builtin_amdgcn_mfma_f32_16x16x32_f16(af[i], bf[jf], acc[i][jf], 0, 0, 0);
  }
  int fq = lane >> 4;
#pragma unroll
  for (int i = 0; i < 4; ++i)
#pragma unroll
    for (int jf = 0; jf < 4; ++jf) {
      int col = wc * 64 + jf * 16 + fr;
      float bv = bias[col];
#pragma unroll
      for (int e = 0; e < 4; ++e) {
        int row = wr * 64 + i * 16 + fq * 4 + e;
        C[(long)row * 1024 + col] = acc[i][jf][e] + bv;
      }
    }
}

// ---------------------------------------------------------------------------
// Encoder v9b (R10-proven, unchanged).
__global__ __launch_bounds__(256, 1) void encoder_k(
    const u16* __restrict__ wenc3, const float* __restrict__ xp,
    u32* hglob,
    float* h0b, float* h1b, float* cfb, float* cbb) {
  int b = blockIdx.x;
  int g16 = ((b >> 7) << 3) | (b & 7);
  int cg = (b >> 3) & 15;
  int d = g16 >> 3, bg = g16 & 7;
  int tid = threadIdx.x, lane = tid & 63, w = tid >> 6;
  int brow = lane & 15, lq = lane >> 4;
  int hswz = (brow & 7) << 4;

  __shared__ __align__(16) char hlds[2][8192];
  __shared__ __align__(16) u16 hstage[16][16];

  f16x8 wfr[8];
  {
    const u16* wb = wenc3 + (((long)d * 16 + cg) * 4 + w) * 4096 + lane * 8;
#pragma unroll
    for (int ks = 0; ks < 8; ++ks)
      wfr[ks] = __builtin_bit_cast(f16x8, *(const u16x8*)(wb + (long)ks * 512));
  }

  float c_state = 0.f;
  long xpbase = ((long)(d * 512) * 128 + bg * 16 + brow) * 1024 + cg * 16 + w * 4 + lq;
  float xpv[4];
#pragma unroll
  for (int g = 0; g < 4; ++g) xpv[g] = xp[xpbase + g * 256];

  u64* hg = (u64*)hglob;
  long ringbase = (long)g16 * 4096;
  int gcg = tid >> 4, gbrow = tid & 15;
  int gldsbase = gbrow * 512 + gcg * 32;
  int gswz = (gbrow & 7) << 4;
  __syncthreads();

  for (int t = 0; t < 512; ++t) {
    if (t != 0) {
      const long gb = ringbase + (long)(t & 3) * 1024 + 4 * tid;
      u64 v0 = SENT, v1 = SENT, v2 = SENT, v3 = SENT;
      for (;;) {
        bool ok = true;
        if (v0 == SENT) { v0 = ald64(hg + gb + 0); ok &= (v0 != SENT); }
        if (v1 == SENT) { v1 = ald64(hg + gb + 1); ok &= (v1 != SENT); }
        if (v2 == SENT) { v2 = ald64(hg + gb + 2); ok &= (v2 != SENT); }
        if (v3 == SENT) { v3 = ald64(hg + gb + 3); ok &= (v3 != SENT); }
        if (ok) break;
      }
      if (tid < 64)
        ast64(hg + ringbase + (long)((t + 2) & 3) * 1024 + cg * 64 + tid, SENT);
      char* hwr = hlds[t & 1];
      *(u32x4*)(hwr + (gldsbase ^ gswz)) =
          (u32x4){ (u32)v0, (u32)(v0 >> 32), (u32)v1, (u32)(v1 >> 32) };
      *(u32x4*)(hwr + ((gldsbase + 16) ^ gswz)) =
          (u32x4){ (u32)v2, (u32)(v2 >> 32), (u32)v3, (u32)(v3 >> 32) };
    }
    __syncthreads();

    f32x4 acc0 = {}, acc1 = {};
    if (t != 0) {
      const char* hrd = hlds[t & 1];
#pragma unroll
      for (int ks = 0; ks < 8; ++ks) {
        f16x8 hf = *(const f16x8*)(hrd + ((brow * 512 + ks * 64 + lq * 16) ^ hswz));
        if (ks & 1) acc1 = __builtin_amdgcn_mfma_f32_16x16x32_f16(wfr[ks], hf, acc1, 0, 0, 0);
        else        acc0 = __builtin_amdgcn_mfma_f32_16x16x32_f16(wfr[ks], hf, acc0, 0, 0, 0);
      }
    }

    float iv = 1.f / (1.f + expf(-(acc0[0] + acc1[0] + xpv[0])));
    float fv = 1.f / (1.f + expf(-(acc0[1] + acc1[1] + xpv[1])));
    float gg = tanhf(acc0[2] + acc1[2] + xpv[2]);
    float ov = 1.f / (1.f + expf(-(acc0[3] + acc1[3] + xpv[3])));
    c_state = fv * c_state + iv * gg;
    float hval = ov * tanhf(c_state);

    if (t < 511) {
      hstage[brow][w * 4 + lq] = f2h(hval);
      __syncthreads();
      asm volatile("s_waitcnt vmcnt(0)" ::: "memory");
      if (tid < 64) {
        u64 v = *(const u64*)&hstage[tid >> 2][(tid & 3) * 4];
        ast64(hg + ringbase + (long)((t + 1) & 3) * 1024 + cg * 64 + tid, v);
      }
      long xb2 = xpbase + (long)(t + 1) * 131072;
#pragma unroll
      for (int g = 0; g < 4; ++g) xpv[g] = xp[xb2 + g * 256];
    } else {
      int rowg = bg * 16 + brow, colg = cg * 16 + w * 4 + lq;
      (d ? h1b : h0b)[32768 + rowg * 256 + colg] = hval;
      (d ? cbb : cfb)[rowg * 256 + colg] = c_state;
    }
  }
}

// ---------------------------------------------------------------------------
// Decoder v3b: 128 blocks = bg(8; blockIdx%8 = XCD residue) x cg(16), 256 thr.
// Each block owns 16 h-cols of BOTH layers: 32 gate-interleaved A-frags =
// 128 VGPR (static idx). Per step two phases, each = MFMA(K=512 from two LDS
// images) + in-register LSTM cell + depth-4 sentinel-ring exchange (v9b
// protocol verbatim: re-arm t+2 -> vmcnt(0) -> store t -> poll/gather).
// hA = h0 image, hB = h1/inp image. Reference carry init: inp0 = ZEROS (not hb)
// -> at t=0 the L0 input-part MFMAs are skipped (contribution exactly 0);
// hB preload = hb serves only L1's h1_init. hist written f32 via staging tile.
__global__ __launch_bounds__(256, 1) void decoder_k(
    const u16* __restrict__ wdec, const float* __restrict__ dbias,
    const float* __restrict__ h0b, const float* __restrict__ h1b,
    const float* __restrict__ cfb, const float* __restrict__ cbb,
    u32* r0, u32* r1, float* __restrict__ hist) {
  int b = blockIdx.x;
  int bg = b & 7, cg = b >> 3;
  int tid = threadIdx.x, lane = tid & 63, w = tid >> 6;
  int brow = lane & 15, lq = lane >> 4;
  int hswz = (brow & 7) << 4;
  int col = cg * 16 + w * 4 + lq;

  __shared__ __align__(16) char hA[8192];   // h0 image [16][256] f16, swizzled
  __shared__ __align__(16) char hB[8192];   // h1 / inp image
  __shared__ __align__(16) u16 hstage[16][16];

  f16x8 w0[16], w1[16];                     // 128 VGPR, statically indexed
  {
    const u16* p0 = wdec + ((long)(cg * 4 + w)) * 8192 + lane * 8;
    const u16* p1 = wdec + ((long)((16 + cg) * 4 + w)) * 8192 + lane * 8;
#pragma unroll
    for (int ks = 0; ks < 16; ++ks) {
      w0[ks] = __builtin_bit_cast(f16x8, *(const u16x8*)(p0 + (long)ks * 512));
      w1[ks] = __builtin_bit_cast(f16x8, *(const u16x8*)(p1 + (long)ks * 512));
    }
  }
  float b0[4], b1[4];
#pragma unroll
  for (int g = 0; g < 4; ++g) {
    b0[g] = dbias[g * 256 + col];
    b1[g] = dbias[1024 + g * 256 + col];
  }
  float c0 = cfb[(bg * 16 + brow) * 256 + col];
  float c1 = cbb[(bg * 16 + brow) * 256 + col];

  int gbrow = tid & 15, gcg = tid >> 4;
  int gldsbase = gbrow * 512 + gcg * 32;
  int gswz = (gbrow & 7) << 4;
  {
    // preload hA = hf (enc fwd final -> h0 init), hB = hb (enc bwd final -> h1 init)
    const float* sA = h0b + 32768 + (bg * 16 + gbrow) * 256 + gcg * 16;
    const float* sB = h1b + 32768 + (bg * 16 + gbrow) * 256 + gcg * 16;
    u32 wa[8], wb[8];
#pragma unroll
    for (int i = 0; i < 8; ++i) {
      wa[i] = packf16(sA[2 * i], sA[2 * i + 1]);
      wb[i] = packf16(sB[2 * i], sB[2 * i + 1]);
    }
    *(u32x4*)(hA + (gldsbase ^ gswz))        = (u32x4){wa[0], wa[1], wa[2], wa[3]};
    *(u32x4*)(hA + ((gldsbase + 16) ^ gswz)) = (u32x4){wa[4], wa[5], wa[6], wa[7]};
    *(u32x4*)(hB + (gldsbase ^ gswz))        = (u32x4){wb[0], wb[1], wb[2], wb[3]};
    *(u32x4*)(hB + ((gldsbase + 16) ^ gswz)) = (u32x4){wb[4], wb[5], wb[6], wb[7]};
  }
  __syncthreads();

  u64* g0 = (u64*)r0;
  u64* g1 = (u64*)r1;
  long ring = (long)bg * 4096;

  for (int t = 0; t < 64; ++t) {
    // ===== L0: gates = [inp | h0_{t-1}] @ W0^T ; inp_0 = 0 (skip hB part) =====
    f32x4 a0 = {}, a1 = {};
    if (t > 0) {
#pragma unroll
      for (int ks = 0; ks < 8; ++ks) {
        f16x8 hf = *(const f16x8*)(hB + ((brow * 512 + ks * 64 + lq * 16) ^ hswz));
        if (ks & 1) a1 = __builtin_amdgcn_mfma_f32_16x16x32_f16(w0[ks], hf, a1, 0, 0, 0);
        else        a0 = __builtin_amdgcn_mfma_f32_16x16x32_f16(w0[ks], hf, a0, 0, 0, 0);
      }
    }
#pragma unroll
    for (int ks = 0; ks < 8; ++ks) {
      f16x8 hf = *(const f16x8*)(hA + ((brow * 512 + ks * 64 + lq * 16) ^ hswz));
      if (ks & 1) a1 = __builtin_amdgcn_mfma_f32_16x16x32_f16(w0[8 + ks], hf, a1, 0, 0, 0);
      else        a0 = __builtin_amdgcn_mfma_f32_16x16x32_f16(w0[8 + ks], hf, a0, 0, 0, 0);
    }
    {
      float iv = 1.f / (1.f + expf(-(a0[0] + a1[0] + b0[0])));
      float fv = 1.f / (1.f + expf(-(a0[1] + a1[1] + b0[1])));
      float gg = tanhf(a0[2] + a1[2] + b0[2]);
      float ov = 1.f / (1.f + expf(-(a0[3] + a1[3] + b0[3])));
      c0 = fv * c0 + iv * gg;
      float h0v = ov * tanhf(c0);
      hstage[brow][w * 4 + lq] = f2h(h0v);
    }
    __syncthreads();
    if (tid < 64)
      ast64(g0 + ring + (long)((t + 2) & 3) * 1024 + cg * 64 + tid, SENT);
    asm volatile("s_waitcnt vmcnt(0)" ::: "memory");
    if (tid < 64) {
      u64 v = *(const u64*)&hstage[tid >> 2][(tid & 3) * 4];
      ast64(g0 + ring + (long)(t & 3) * 1024 + cg * 64 + tid, v);
    }
    {
      const long gb = ring + (long)(t & 3) * 1024 + 4 * tid;
      u64 v0 = SENT, v1 = SENT, v2 = SENT, v3 = SENT;
      for (;;) {
        bool ok = true;
        if (v0 == SENT) { v0 = ald64(g0 + gb + 0); ok &= (v0 != SENT); }
        if (v1 == SENT) { v1 = ald64(g0 + gb + 1); ok &= (v1 != SENT); }
        if (v2 == SENT) { v2 = ald64(g0 + gb + 2); ok &= (v2 != SENT); }
        if (v3 == SENT) { v3 = ald64(g0 + gb + 3); ok &= (v3 != SENT); }
        if (ok) break;
      }
      *(u32x4*)(hA + (gldsbase ^ gswz)) =
          (u32x4){ (u32)v0, (u32)(v0 >> 32), (u32)v1, (u32)(v1 >> 32) };
      *(u32x4*)(hA + ((gldsbase + 16) ^ gswz)) =
          (u32x4){ (u32)v2, (u32)(v2 >> 32), (u32)v3, (u32)(v3 >> 32) };
    }
    __syncthreads();

    // ===== L1: gates = [hA(h0_t) | hB(h1_{t-1})] @ W1^T =====
    a0 = (f32x4){}; a1 = (f32x4){};
#pragma unroll
    for (int ks = 0; ks < 8; ++ks) {
      f16x8 hf = *(const f16x8*)(hA + ((brow * 512 + ks * 64 + lq * 16) ^ hswz));
      if (ks & 1) a1 = __builtin_amdgcn_mfma_f32_16x16x32_f16(w1[ks], hf, a1, 0, 0, 0);
      else        a0 = __builtin_amdgcn_mfma_f32_16x16x32_f16(w1[ks], hf, a0, 0, 0, 0);
    }
#pragma unroll
    for (int ks = 0; ks < 8; ++ks) {
      f16x8 hf = *(const f16x8*)(hB + ((brow * 512 + ks * 64 + lq * 16) ^ hswz));
      if (ks & 1) a1 = __builtin_amdgcn_mfma_f32_16x16x32_f16(w1[8 + ks], hf, a1, 0, 0, 0);
      else        a0 = __builtin_amdgcn_mfma_f32_16x16x32_f16(w1[8 + ks], hf, a0, 0, 0, 0);
    }
    {
      float iv = 1.f / (1.f + expf(-(a0[0] + a1[0] + b1[0])));
      float fv = 1.f / (1.f + expf(-(a0[1] + a1[1] + b1[1])));
      float gg = tanhf(a0[2] + a1[2] + b1[2]);
      float ov = 1.f / (1.f + expf(-(a0[3] + a1[3] + b1[3])));
      c1 = fv * c1 + iv * gg;
      float h1v = ov * tanhf(c1);
      hstage[brow][w * 4 + lq] = f2h(h1v);
    }
    __syncthreads();
    if (tid < 64) {   // hist: f32, staged 16B per thread
      u64 v = *(const u64*)&hstage[tid >> 2][(tid & 3) * 4];
      float4 hv4 = { h2f((u16)v), h2f((u16)(v >> 16)),
                     h2f((u16)(v >> 32)), h2f((u16)(v >> 48)) };
      *(float4*)&hist[((long)t * 128 + bg * 16 + (tid >> 2)) * 256 + cg * 16 + (tid & 3) * 4] = hv4;
    }
    if (t < 63) {
      if (tid < 64)
        ast64(g1 + ring + (long)((t + 2) & 3) * 1024 + cg * 64 + tid, SENT);
      asm volatile("s_waitcnt vmcnt(0)" ::: "memory");
      if (tid < 64) {
        u64 v = *(const u64*)&hstage[tid >> 2][(tid & 3) * 4];
        ast64(g1 + ring + (long)(t & 3) * 1024 + cg * 64 + tid, v);
      }
      const long gb = ring + (long)(t & 3) * 1024 + 4 * tid;
      u64 v0 = SENT, v1 = SENT, v2 = SENT, v3 = SENT;
      for (;;) {
        bool ok = true;
        if (v0 == SENT) { v0 = ald64(g1 + gb + 0); ok &= (v0 != SENT); }
        if (v1 == SENT) { v1 = ald64(g1 + gb + 1); ok &= (v1 != SENT); }
        if (v2 == SENT) { v2 = ald64(g1 + gb + 2); ok &= (v2 != SENT); }
        if (v3 == SENT) { v3 = ald64(g1 + gb + 3); ok &= (v3 != SENT); }
        if (ok) break;
      }
      *(u32x4*)(hB + (gldsbase ^ gswz)) =
          (u32x4){ (u32)v0, (u32)(v0 >> 32), (u32)v1, (u32)(v1 >> 32) };
      *(u32x4*)(hB + ((gldsbase + 16) ^ gswz)) =
          (u32x4){ (u32)v2, (u32)(v2 >> 32), (u32)v3, (u32)(v3 >> 32) };
    }
    __syncthreads();
  }
}

// ---------------------------------------------------------------------------
__global__ __launch_bounds__(256) void logits_k(
    const float* __restrict__ hist, const float* __restrict__ lw,
    const float* __restrict__ lb, float* __restrict__ out) {
  int widx = threadIdx.x >> 6, lane = threadIdx.x & 63;
  int row = blockIdx.x * 4 + widx;
  const float* h = hist + (long)row * 256;
  float4 hv = *(const float4*)&h[lane * 4];
  float s[3];
#pragma unroll
  for (int v = 0; v < 3; ++v) {
    float4 wv = *(const float4*)&lw[v * 256 + lane * 4];
    float p = hv.x * wv.x + hv.y * wv.y + hv.z * wv.z + hv.w * wv.w;
#pragma unroll
    for (int o = 32; o > 0; o >>= 1) p += __shfl_xor(p, o, 64);
    s[v] = p;
  }
  if (lane == 0) {
    out[row * 3 + 0] = s[0] + lb[0];
    out[row * 3 + 1] = s[1] + lb[1];
    out[row * 3 + 2] = s[2] + lb[2];
  }
}

// ---------------------------------------------------------------------------
extern "C" void kernel_launch(void* const* d_in, const int* in_sizes, int n_in,
                              void* d_out, int out_size, void* d_ws, size_t ws_size,
                              hipStream_t stream) {
  const float* x     = (const float*)d_in[0];
  const float* ewihf = (const float*)d_in[1];
  const float* ewhhf = (const float*)d_in[2];
  const float* ebihf = (const float*)d_in[3];
  const float* ebhhf = (const float*)d_in[4];
  const float* ewihb = (const float*)d_in[5];
  const float* ewhhb = (const float*)d_in[6];
  const float* ebihb = (const float*)d_in[7];
  const float* ebhhb = (const float*)d_in[8];
  const float* dwih0 = (const float*)d_in[9];
  const float* dwhh0 = (const float*)d_in[10];
  const float* dbih0 = (const float*)d_in[11];
  const float* dbhh0 = (const float*)d_in[12];
  const float* dwih1 = (const float*)d_in[13];
  const float* dwhh1 = (const float*)d_in[14];
  const float* dbih1 = (const float*)d_in[15];
  const float* dbhh1 = (const float*)d_in[16];
  const float* lw    = (const float*)d_in[17];
  const float* lb    = (const float*)d_in[18];
  float* out = (float*)d_out;
  (void)in_sizes; (void)n_in; (void)out_size; (void)ws_size;

  char* wsb = (char*)d_ws;
  size_t off = 0;
  auto take = [&](size_t bytes) -> char* {
    char* p = wsb + off;
    off = (off + bytes + 255) & ~(size_t)255;
    return p;
  };
  u16*   xh    = (u16*)take(67108864ull * 2);    // x f16
  u16*   whx   = (u16*)take(2097152ull * 2);     // ew_ih f,b f16
  float* xp    = (float*)take(134217728ull * 4); // Xproj [2][512][128][1024] fp32
  u16*   wenc3 = (u16*)take(524288ull * 2);      // enc W_hh gate-interleaved frags
  u16*   wdec  = (u16*)take(1048576ull * 2);     // dec both-layer gate-interleaved frags
  float* bias2 = (float*)take(2048 * 4);
  float* dbias = (float*)take(2048 * 4);
  u32*   hglob = (u32*)take(131072ull * 4);      // enc h ring [16g][4 slot][1024 u64]
  u32*   r0    = (u32*)take(65536ull * 4);       // dec h0 ring [8g][4 slot][1024 u64]
  u32*   r1    = (u32*)take(65536ull * 4);       // dec h1 ring
  float* h0b   = (float*)take(65536 * 4);
  float* h1b   = (float*)take(65536 * 4);
  float* cfb   = (float*)take(32768 * 4);
  float* cbb   = (float*)take(32768 * 4);
  float* hist  = (float*)take(2097152 * 4);      // h1 history [64][128][256] f32

  init_k<<<1024, 256, 0, stream>>>(hglob, r0, r1);
  convert_k<<<2048, 256, 0, stream>>>(x, ewihf, ewihb, ebihf, ebhhf, ebihb, ebhhb,
                                      dbih0, dbhh0, dbih1, dbhh1, xh, whx, bias2, dbias);
  convert_we3_k<<<2048, 256, 0, stream>>>(ewhhf, ewhhb, wenc3);
  convert_wdec_k<<<4096, 256, 0, stream>>>(dwih0, dwhh0, dwih1, dwhh1, wdec);
  xproj_gemm<<<8192, 256, 0, stream>>>(xh, whx, bias2, xp);
  encoder_k<<<256, 256, 0, stream>>>(wenc3, xp, hglob, h0b, h1b, cfb, cbb);
  decoder_k<<<128, 256, 0, stream>>>(wdec, dbias, h0b, h1b, cfb, cbb, r0, r1, hist);
  logits_k<<<2048, 256, 0, stream>>>(hist, lw, lb, out);
}